// Round 9
// baseline (253.908 us; speedup 1.0000x reference)
//
#include <hip/hip_runtime.h>
#include <hip/hip_bf16.h>
#include <stdint.h>

namespace {
constexpr int CB = 2, CS = 2048, CD = 2048, CH = 32, CG = 8, CHD = 64, CGS = 4;

typedef __bf16 bf16x8 __attribute__((ext_vector_type(8)));
typedef float f32x4 __attribute__((ext_vector_type(4)));
typedef float f32x16 __attribute__((ext_vector_type(16)));
typedef uint32_t u32x4 __attribute__((ext_vector_type(4)));

__device__ inline uint16_t f2bf(float f) {
  uint32_t u = __float_as_uint(f);
  u += 0x7fffu + ((u >> 16) & 1u);
  return (uint16_t)(u >> 16);
}

__device__ inline void gload_lds16(const void* g, void* l) {
  __builtin_amdgcn_global_load_lds(
      (const __attribute__((address_space(1))) void*)g,
      (__attribute__((address_space(3))) void*)l, 16, 0, 0);
}

__device__ inline uint32_t cvtpk_bf16(float lo, float hi) {
  uint32_t r;
  asm("v_cvt_pk_bf16_f32 %0, %1, %2" : "=v"(r) : "v"(lo), "v"(hi));
  return r;
}
// in-place: a <- {a.lo, b.lo}, b <- {a.hi, b.hi}
__device__ inline void pl32swap(uint32_t& a, uint32_t& b) {
  asm("v_permlane32_swap_b32 %0, %1" : "+v"(a), "+v"(b));
}
}  // namespace

// ------------- fused cast f32 -> bf16 for x and kv -------------
__global__ __launch_bounds__(256) void cast_both_kernel(
    const float* __restrict__ x, const float* __restrict__ kv,
    uint16_t* __restrict__ xb, uint16_t* __restrict__ kvb, int nel) {
  int i = (blockIdx.x * 256 + threadIdx.x) * 4;
  const float* in;
  uint16_t* out;
  if (i < nel) { in = x + i; out = xb + i; }
  else         { in = kv + (i - nel); out = kvb + (i - nel); }
  const float4 v = *(const float4*)in;
  ushort4 o;
  o.x = f2bf(v.x); o.y = f2bf(v.y); o.z = f2bf(v.z); o.w = f2bf(v.w);
  *(ushort4*)out = o;
}

// ------------- fused transpose+cast of all 4 weights into [5120][2048] ----
// rows 0..2047: WqT, 2048..2559: WkT, 2560..3071: WvT, 3072..5119: WoT
__global__ __launch_bounds__(256) void transpose_all_kernel(
    const float* __restrict__ Wq, const float* __restrict__ Wk,
    const float* __restrict__ Wv, const float* __restrict__ Wo,
    uint16_t* __restrict__ out) {
  __shared__ uint16_t tile[32][33];
  const int gn0 = blockIdx.x * 32;  // output row block (0..5119)
  const int k0 = blockIdx.y * 32;
  const float* in;
  int Nr, start;
  if (gn0 < 2048)      { in = Wq; Nr = 2048; start = 0; }
  else if (gn0 < 2560) { in = Wk; Nr = 512;  start = 2048; }
  else if (gn0 < 3072) { in = Wv; Nr = 512;  start = 2560; }
  else                 { in = Wo; Nr = 2048; start = 3072; }
  const int n0 = gn0 - start;
  const int tx = threadIdx.x & 31, tg = threadIdx.x >> 5;
#pragma unroll
  for (int rr = 0; rr < 4; ++rr) {
    int k = tg * 4 + rr;
    tile[k][tx] = f2bf(in[(size_t)(k0 + k) * Nr + n0 + tx]);
  }
  __syncthreads();
#pragma unroll
  for (int rr = 0; rr < 4; ++rr) {
    int n = tg * 4 + rr;
    out[(size_t)(gn0 + n) * CD + k0 + tx] = tile[tx][n];
  }
}

// ------------- fused QKV projection GEMM (R5 config: best measured) ------
// 128x128 tile, BK=32, 256 thr / 4 waves, triple-buffered LDS (48 KiB ->
// 3 blocks/CU), counted vmcnt (never 0 in loop).
// C[4096, 3072] = A_sel[M,K] * WT[3072,K]^T + bias_sel ; region by n0:
//   n in [0,2048):    A=xb,  bias=bq, out Q[B,H,S,HD] scaled by 1/8*log2e
//   n in [2048,2560): A=kvb, bias=bk, out K[B,G,S,HD]
//   n in [2560,3072): A=kvb, bias=bv, out VT[B,G,HD,S]
__global__ __launch_bounds__(256, 2) void gemm_qkv_kernel(
    const uint16_t* __restrict__ xb, const uint16_t* __restrict__ kvb,
    const uint16_t* __restrict__ WT,
    const float* __restrict__ bq, const float* __restrict__ bk,
    const float* __restrict__ bv,
    uint16_t* __restrict__ Qb, uint16_t* __restrict__ Kb,
    uint16_t* __restrict__ VTb) {
  constexpr int BM = 128, BN = 128, BK = 32, K = 2048, NT = K / BK;  // 64
  constexpr int ASZ = BM * BK;       // 4096 elems
  constexpr int BSZ = BN * BK;       // 4096 elems
  constexpr int BUFSZ = ASZ + BSZ;   // 16 KB per K-tile
  __shared__ uint16_t smem[3 * BUFSZ];  // 48 KB -> 3 blocks/CU
  const int tid = threadIdx.x;
  const int w = tid >> 6, l = tid & 63;
  const int wr = w >> 1, wc = w & 1;   // 2M x 2N waves; per-wave 64x64
  const int l15 = l & 15, lq = l >> 4;

  // XCD-aware bijective swizzle (nwg = 768, divisible by 8)
  const int gx = gridDim.x;  // 24
  int bid = blockIdx.y * gx + blockIdx.x;
  const int nwg = gx * gridDim.y;
  bid = (bid & 7) * (nwg >> 3) + (bid >> 3);
  const int m0 = (bid / gx) * BM, n0 = (bid % gx) * BN;
  const uint16_t* A = (n0 < 2048) ? xb : kvb;

  // conflict-free swizzle for 64B rows: kq = slot ^ ((row>>1)&3)
  // (verified 0 bank conflicts); same involution on stage-src and ds_read.
  auto stage = [&](int buf, int kt) {
    uint16_t* base = smem + buf * BUFSZ;
    const int k0 = kt * BK;
#pragma unroll
    for (int i = 0; i < 2; ++i) {
      int g = i * 256 + tid;            // A granules 0..511 (128 rows x 4)
      int row = g >> 2, slot = g & 3;
      int kq = slot ^ ((row >> 1) & 3);
      gload_lds16(A + (size_t)(m0 + row) * K + k0 + kq * 8, base + g * 8);
    }
#pragma unroll
    for (int i = 0; i < 2; ++i) {
      int g = i * 256 + tid;            // B granules
      int row = g >> 2, slot = g & 3;
      int kq = slot ^ ((row >> 1) & 3);
      gload_lds16(WT + (size_t)(n0 + row) * K + k0 + kq * 8,
                  base + ASZ + g * 8);
    }
  };

  // swizzled LDS read byte-offsets (tile-invariant)
  int aOff[4], bOff[4];
#pragma unroll
  for (int m = 0; m < 4; ++m) {
    int row = wr * 64 + m * 16 + l15;
    aOff[m] = (row * BK + (lq ^ ((row >> 1) & 3)) * 8) * 2;
  }
#pragma unroll
  for (int n = 0; n < 4; ++n) {
    int row = wc * 64 + n * 16 + l15;
    bOff[n] = ASZ * 2 + (row * BK + (lq ^ ((row >> 1) & 3)) * 8) * 2;
  }

  f32x4 acc[4][4] = {};

  stage(0, 0);
  stage(1, 1);

  int bt = 0, bs = 2;  // compute buffer (t%3), stage buffer ((t+2)%3)
  for (int t = 0; t < NT; ++t) {
    // tile t landed when <= (loads of tile t+1 = 4) remain outstanding
    if (t < NT - 1) asm volatile("s_waitcnt vmcnt(4)" ::: "memory");
    else            asm volatile("s_waitcnt vmcnt(0)" ::: "memory");
    __builtin_amdgcn_s_barrier();
    asm volatile("" ::: "memory");

    const char* buf = (const char*)(smem + bt * BUFSZ);
    bf16x8 af[4], bfr[4];
#pragma unroll
    for (int m = 0; m < 4; ++m) af[m] = *(const bf16x8*)(buf + aOff[m]);
#pragma unroll
    for (int n = 0; n < 4; ++n) bfr[n] = *(const bf16x8*)(buf + bOff[n]);

    if (t + 2 < NT) stage(bs, t + 2);  // buffer of t-1: dead past the barrier

    __builtin_amdgcn_s_setprio(1);
#pragma unroll
    for (int m = 0; m < 4; ++m)
#pragma unroll
      for (int n = 0; n < 4; ++n)
        acc[m][n] = __builtin_amdgcn_mfma_f32_16x16x32_bf16(
            af[m], bfr[n], acc[m][n], 0, 0, 0);
    __builtin_amdgcn_s_setprio(0);

    bt = bt == 2 ? 0 : bt + 1;
    bs = bs == 2 ? 0 : bs + 1;
  }

#pragma unroll
  for (int m = 0; m < 4; ++m)
#pragma unroll
    for (int n = 0; n < 4; ++n)
#pragma unroll
      for (int r = 0; r < 4; ++r) {
        int gm = m0 + wr * 64 + m * 16 + lq * 4 + r;
        int gn = n0 + wc * 64 + n * 16 + l15;
        int b = gm >> 11, s = gm & (CS - 1);
        if (n0 < 2048) {  // Q (pre-scaled)
          float v = (acc[m][n][r] + bq[gn]) * (0.125f * 1.44269504088896340736f);
          int h = gn >> 6, hd = gn & 63;
          Qb[(((size_t)(b * CH + h)) * CS + s) * CHD + hd] = f2bf(v);
        } else if (n0 < 2560) {  // K
          int gn2 = gn - 2048;
          float v = acc[m][n][r] + bk[gn2];
          int gh = gn2 >> 6, hd = gn2 & 63;
          Kb[(((size_t)(b * CG + gh)) * CS + s) * CHD + hd] = f2bf(v);
        } else {  // V -> VT[B,G,HD,S]
          int gn2 = gn - 2560;
          float v = acc[m][n][r] + bv[gn2];
          int gh = gn2 >> 6, hd = gn2 & 63;
          VTb[(((size_t)(b * CG + gh)) * CHD + hd) * CS + s] = f2bf(v);
        }
      }
}

// ------------- output projection GEMM (R5 config) ------------------------
__global__ __launch_bounds__(256, 2) void gemm_out_kernel(
    const uint16_t* __restrict__ A, const uint16_t* __restrict__ Bt,
    const float* __restrict__ bias, float* __restrict__ Cout,
    int M, int N, int Kdim) {
  constexpr int BM = 128, BN = 128, BK = 32, K = 2048, NT = K / BK;  // 64
  constexpr int ASZ = BM * BK;       // 4096 elems
  constexpr int BSZ = BN * BK;       // 4096 elems
  constexpr int BUFSZ = ASZ + BSZ;   // 16 KB per K-tile
  __shared__ uint16_t smem[3 * BUFSZ];  // 48 KB
  const int tid = threadIdx.x;
  const int w = tid >> 6, l = tid & 63;
  const int wr = w >> 1, wc = w & 1;   // per-wave 64x64
  const int l15 = l & 15, lq = l >> 4;

  // XCD-aware bijective swizzle (nwg = 512, divisible by 8)
  const int gx = gridDim.x;  // 16
  int bid = blockIdx.y * gx + blockIdx.x;
  const int nwg = gx * gridDim.y;
  bid = (bid & 7) * (nwg >> 3) + (bid >> 3);
  const int m0 = (bid / gx) * BM, n0 = (bid % gx) * BN;

  auto stage = [&](int buf, int kt) {
    uint16_t* base = smem + buf * BUFSZ;
    const int k0 = kt * BK;
#pragma unroll
    for (int i = 0; i < 2; ++i) {
      int g = i * 256 + tid;
      int row = g >> 2, slot = g & 3;
      int kq = slot ^ ((row >> 1) & 3);
      gload_lds16(A + (size_t)(m0 + row) * K + k0 + kq * 8, base + g * 8);
    }
#pragma unroll
    for (int i = 0; i < 2; ++i) {
      int g = i * 256 + tid;
      int row = g >> 2, slot = g & 3;
      int kq = slot ^ ((row >> 1) & 3);
      gload_lds16(Bt + (size_t)(n0 + row) * K + k0 + kq * 8,
                  base + ASZ + g * 8);
    }
  };

  int aOff[4], bOff[4];
#pragma unroll
  for (int m = 0; m < 4; ++m) {
    int row = wr * 64 + m * 16 + l15;
    aOff[m] = (row * BK + (lq ^ ((row >> 1) & 3)) * 8) * 2;
  }
#pragma unroll
  for (int n = 0; n < 4; ++n) {
    int row = wc * 64 + n * 16 + l15;
    bOff[n] = ASZ * 2 + (row * BK + (lq ^ ((row >> 1) & 3)) * 8) * 2;
  }

  f32x4 acc[4][4] = {};

  stage(0, 0);
  stage(1, 1);

  int bt = 0, bs = 2;
  for (int t = 0; t < NT; ++t) {
    if (t < NT - 1) asm volatile("s_waitcnt vmcnt(4)" ::: "memory");
    else            asm volatile("s_waitcnt vmcnt(0)" ::: "memory");
    __builtin_amdgcn_s_barrier();
    asm volatile("" ::: "memory");

    const char* buf = (const char*)(smem + bt * BUFSZ);
    bf16x8 af[4], bfr[4];
#pragma unroll
    for (int m = 0; m < 4; ++m) af[m] = *(const bf16x8*)(buf + aOff[m]);
#pragma unroll
    for (int n = 0; n < 4; ++n) bfr[n] = *(const bf16x8*)(buf + bOff[n]);

    if (t + 2 < NT) stage(bs, t + 2);

    __builtin_amdgcn_s_setprio(1);
#pragma unroll
    for (int m = 0; m < 4; ++m)
#pragma unroll
      for (int n = 0; n < 4; ++n)
        acc[m][n] = __builtin_amdgcn_mfma_f32_16x16x32_bf16(
            af[m], bfr[n], acc[m][n], 0, 0, 0);
    __builtin_amdgcn_s_setprio(0);

    bt = bt == 2 ? 0 : bt + 1;
    bs = bs == 2 ? 0 : bs + 1;
  }

#pragma unroll
  for (int m = 0; m < 4; ++m)
#pragma unroll
    for (int n = 0; n < 4; ++n)
#pragma unroll
      for (int r = 0; r < 4; ++r) {
        int gm = m0 + wr * 64 + m * 16 + lq * 4 + r;
        int gn = n0 + wc * 64 + n * 16 + l15;
        Cout[(size_t)gm * N + gn] = acc[m][n][r] + bias[gn];
      }
}

// ---------------- causal flash attention, 32x32 MFMA ---------------------
// ONE q-block (128 rows) per block, grid.x = 16 -> 1024 blocks = 2x the
// wave-parallelism of the paired layout. Balance via INTERLEAVED mapping:
// qb = x&1 ? x>>1 : 15-(x>>1) -> dispatch order 15,0,14,1,... so adjacent
// blocks (adjacent CU slots) carry complementary work (fixes R7's LPT
// pileup). K/V triple-buffered (48 KiB -> 3 blocks/CU), counted vmcnt.
// Q[B,H,S,HD] bf16 (pre-scaled), K[B,G,S,HD] bf16, VT[B,G,HD,S] bf16
__global__ __launch_bounds__(256) void flash_attn_kernel(
    const uint16_t* __restrict__ Q, const uint16_t* __restrict__ K,
    const uint16_t* __restrict__ VT, uint16_t* __restrict__ Aout) {
  constexpr int NQB = CS / 128;  // 16
  __shared__ __align__(16) uint16_t Ksm[3][64 * 64];  // [key][hd] swizzled
  __shared__ __align__(16) uint16_t Vsm[3][64 * 64];  // [hd][key] swizzled
  const int tid = threadIdx.x, w = tid >> 6, l = tid & 63;
  const int l31 = l & 31, hi = l >> 5;
  const int x = blockIdx.x;  // 0..NQB-1
  const int qb = (x & 1) ? (x >> 1) : (NQB - 1 - (x >> 1));  // interleaved
  const int h = blockIdx.y, b = blockIdx.z, g = h >> 2;

  const uint16_t* Qbase = Q + ((size_t)(b * CH + h)) * CS * CHD;
  const uint16_t* Kbase = K + ((size_t)(b * CG + g)) * CS * CHD;
  const uint16_t* Vbase = VT + ((size_t)(b * CG + g)) * CHD * CS;

  // ---- staging addresses (kt-invariant) ----
  const int srow = tid >> 3, sslot = tid & 7;
  const int skq = sslot ^ (srow & 7);
  const uint16_t* kSrc0 = Kbase + (size_t)srow * CHD + skq * 8;
  const uint16_t* kSrc1 = kSrc0 + 32 * CHD;            // row+32: same XOR
  const uint16_t* vSrc0 = Vbase + (size_t)srow * CS + skq * 8;
  const uint16_t* vSrc1 = vSrc0 + 32 * CS;
  uint16_t* kDst0 = &Ksm[0][0] + tid * 8;
  uint16_t* vDst0 = &Vsm[0][0] + tid * 8;

  // ---- swizzled LDS read offsets (kt-invariant) ----
  int qkOff[2][4];
#pragma unroll
  for (int c = 0; c < 2; ++c)
#pragma unroll
    for (int kc = 0; kc < 4; ++kc) {
      int row = c * 32 + l31;
      qkOff[c][kc] = ((row * 64 + kc * 16 + hi * 8) * 2) ^ ((row & 7) << 4);
    }

  auto stage = [&](int buf, int kt) {
    const size_t ko = (size_t)kt * 64 * CHD;
    const int vo = kt * 64;
    uint16_t* kd = kDst0 + buf * 64 * 64;
    uint16_t* vd = vDst0 + buf * 64 * 64;
    gload_lds16(kSrc0 + ko, kd);
    gload_lds16(kSrc1 + ko, kd + 2048);  // granule tid+256 -> elem +2048
    gload_lds16(vSrc0 + vo, vd);
    gload_lds16(vSrc1 + vo, vd + 2048);
  };

  const int qrow = qb * 128 + w * 32 + l31;
  const int wtop = qb * 128 + w * 32 + 31;

  // Q B-frags: qf[kc] elem j = Q[qrow][kc*16 + hi*8 + j]
  bf16x8 qf[4];
#pragma unroll
  for (int kc = 0; kc < 4; ++kc)
    qf[kc] = *(const bf16x8*)(Qbase + (size_t)qrow * CHD + kc * 16 + hi * 8);

  f32x16 o0 = {}, o1 = {};
  float mrun = -3e38f, lrun = 0.f;
  const int nt = 2 * qb + 2;  // >= 2 always

  stage(0, 0);
  stage(1, 1);

  int bt = 0, bs = 2;  // compute buffer (kt%3), stage buffer ((kt+2)%3)
  for (int kt = 0; kt < nt; ++kt) {
    // tile kt landed when <= (loads of tile kt+1 = 4) remain outstanding
    if (kt < nt - 1) asm volatile("s_waitcnt vmcnt(4)" ::: "memory");
    else             asm volatile("s_waitcnt vmcnt(0)" ::: "memory");
    __builtin_amdgcn_s_barrier();
    asm volatile("" ::: "memory");

    if (kt + 2 < nt) stage(bs, kt + 2);  // buffer of kt-1: dead past barrier

    if (kt * 64 <= wtop) {
      const char* ksmb = (const char*)Ksm[bt];
      const char* vsmb = (const char*)Vsm[bt];

      // swapped QK^T: p[c] = K_chunk_c * Q -> P[key=crow+32c][q=l31]
      f32x16 p0 = {}, p1 = {};
      __builtin_amdgcn_s_setprio(1);
#pragma unroll
      for (int kc = 0; kc < 4; ++kc) {
        bf16x8 ka0 = *(const bf16x8*)(ksmb + qkOff[0][kc]);
        bf16x8 ka1 = *(const bf16x8*)(ksmb + qkOff[1][kc]);
        p0 = __builtin_amdgcn_mfma_f32_32x32x16_bf16(ka0, qf[kc], p0, 0, 0, 0);
        p1 = __builtin_amdgcn_mfma_f32_32x32x16_bf16(ka1, qf[kc], p1, 0, 0, 0);
      }
      __builtin_amdgcn_s_setprio(0);

      // causal mask (diag tiles only) + per-lane online softmax
      const bool need_mask = (kt * 64 + 63 > qb * 128 + w * 32);
      float pmax = -3e38f;
      if (need_mask) {
#pragma unroll
        for (int r = 0; r < 16; ++r) {
          int keyb = kt * 64 + (r & 3) + 8 * (r >> 2) + 4 * hi;
          if (keyb > qrow) p0[r] = -3e38f;
          if (keyb + 32 > qrow) p1[r] = -3e38f;
        }
      }
#pragma unroll
      for (int r = 0; r < 16; ++r) {
        pmax = fmaxf(pmax, p0[r]);
        pmax = fmaxf(pmax, p1[r]);
      }
      pmax = fmaxf(pmax, __shfl_xor(pmax, 32));

      // defer-max: skip O-rescale unless max grew past threshold
      if (!__all(pmax <= mrun + 8.f)) {
        float mnew = fmaxf(mrun, pmax);
        float alpha = __builtin_amdgcn_exp2f(mrun - mnew);
#pragma unroll
        for (int r = 0; r < 16; ++r) { o0[r] *= alpha; o1[r] *= alpha; }
        lrun *= alpha;
        mrun = mnew;
      }
      float s = 0.f;
#pragma unroll
      for (int r = 0; r < 16; ++r) {
        float e0 = __builtin_amdgcn_exp2f(p0[r] - mrun);
        float e1 = __builtin_amdgcn_exp2f(p1[r] - mrun);
        p0[r] = e0; p1[r] = e1;
        s += e0 + e1;
      }
      s += __shfl_xor(s, 32);
      lrun += s;

      // P -> bf16 B-frags in-register (cvt_pk + permlane32_swap)
      u32x4 paw[4];
#pragma unroll
      for (int k = 0; k < 4; ++k) {
        const int base = (k & 1) * 8;
        const f32x16& pc = (k >> 1) ? p1 : p0;
        uint32_t c01 = cvtpk_bf16(pc[base + 0], pc[base + 1]);
        uint32_t c23 = cvtpk_bf16(pc[base + 2], pc[base + 3]);
        uint32_t c45 = cvtpk_bf16(pc[base + 4], pc[base + 5]);
        uint32_t c67 = cvtpk_bf16(pc[base + 6], pc[base + 7]);
        pl32swap(c01, c45);
        pl32swap(c23, c67);
        paw[k] = (u32x4){c01, c23, c45, c67};
      }

      // PV (swapped): o[hc] += V^T_chunk * P
      __builtin_amdgcn_s_setprio(1);
#pragma unroll
      for (int ks = 0; ks < 4; ++ks) {
        bf16x8 vb0 = *(const bf16x8*)(vsmb + qkOff[0][ks]);
        bf16x8 vb1 = *(const bf16x8*)(vsmb + qkOff[1][ks]);
        bf16x8 pb = __builtin_bit_cast(bf16x8, paw[ks]);
        o0 = __builtin_amdgcn_mfma_f32_32x32x16_bf16(vb0, pb, o0, 0, 0, 0);
        o1 = __builtin_amdgcn_mfma_f32_32x32x16_bf16(vb1, pb, o1, 0, 0, 0);
      }
      __builtin_amdgcn_s_setprio(0);
    }

    bt = bt == 2 ? 0 : bt + 1;
    bs = bs == 2 ? 0 : bs + 1;
  }

  // epilogue: lane owns q-row qrow; cols hd = crow(reg,hi)+32*hc
  float invl = 1.f / lrun;
  uint16_t* orow = Aout + ((size_t)b * CS + qrow) * CD + (size_t)h * CHD;
#pragma unroll
  for (int k = 0; k < 8; ++k) {
    int reg = 2 * k;
    int hd = (reg & 3) + 8 * (reg >> 2) + 4 * hi;
    *(uint32_t*)(orow + hd) = cvtpk_bf16(o0[reg] * invl, o0[reg + 1] * invl);
    *(uint32_t*)(orow + hd + 32) = cvtpk_bf16(o1[reg] * invl, o1[reg + 1] * invl);
  }
}

extern "C" void kernel_launch(void* const* d_in, const int* in_sizes, int n_in,
                              void* d_out, int out_size, void* d_ws, size_t ws_size,
                              hipStream_t stream) {
  const float* x = (const float*)d_in[0];
  const float* kv = (const float*)d_in[1];
  const float* Wq = (const float*)d_in[2];
  const float* bq = (const float*)d_in[3];
  const float* Wk = (const float*)d_in[4];
  const float* bk = (const float*)d_in[5];
  const float* Wv = (const float*)d_in[6];
  const float* bv = (const float*)d_in[7];
  const float* Wo = (const float*)d_in[8];
  const float* bo = (const float*)d_in[9];
  float* out = (float*)d_out;

  char* ws = (char*)d_ws;
  uint16_t* xb = (uint16_t*)ws;   ws += (size_t)CB * CS * CD * 2;
  uint16_t* kvb = (uint16_t*)ws;  ws += (size_t)CB * CS * CD * 2;
  uint16_t* WqT = (uint16_t*)ws;  ws += (size_t)CD * CD * 2;        // rows 0..2047
  uint16_t* WkT = (uint16_t*)ws;  ws += (size_t)(CG * CHD) * CD * 2;  // 2048..2559
  uint16_t* WvT = (uint16_t*)ws;  ws += (size_t)(CG * CHD) * CD * 2;  // 2560..3071
  uint16_t* WoT = (uint16_t*)ws;  ws += (size_t)CD * CD * 2;        // 3072..5119
  uint16_t* Qb = (uint16_t*)ws;   ws += (size_t)CB * CH * CS * CHD * 2;
  uint16_t* Kb = (uint16_t*)ws;   ws += (size_t)CB * CG * CS * CHD * 2;
  uint16_t* VTb = (uint16_t*)ws;  ws += (size_t)CB * CG * CHD * CS * 2;
  uint16_t* attnb = (uint16_t*)ws;
  (void)WkT; (void)WvT;

  const int NTOK = CB * CS;  // 4096
  const int nel = CB * CS * CD;

  cast_both_kernel<<<2 * nel / 4 / 256, 256, 0, stream>>>(x, kv, xb, kvb, nel);
  transpose_all_kernel<<<dim3(5120 / 32, CD / 32), 256, 0, stream>>>(
      Wq, Wk, Wv, Wo, WqT);

  gemm_qkv_kernel<<<dim3(3072 / 128, NTOK / 128), 256, 0, stream>>>(
      xb, kvb, WqT, bq, bk, bv, Qb, Kb, VTb);

  flash_attn_kernel<<<dim3(CS / 128, CH, CB), 256, 0, stream>>>(Qb, Kb, VTb, attnb);

  gemm_out_kernel<<<dim3(CD / 128, NTOK / 128), 256, 0, stream>>>(
      attnb, WoT, bo, out, NTOK, CD, CD);
}

// Round 11
// 200.651 us; speedup vs baseline: 1.2654x; 1.2654x over previous
//
#include <hip/hip_runtime.h>
#include <hip/hip_bf16.h>
#include <stdint.h>

namespace {
constexpr int CB = 2, CS = 2048, CD = 2048, CH = 32, CG = 8, CHD = 64, CGS = 4;

typedef __bf16 bf16x8 __attribute__((ext_vector_type(8)));
typedef float f32x4 __attribute__((ext_vector_type(4)));
typedef float f32x16 __attribute__((ext_vector_type(16)));
typedef uint32_t u32x4 __attribute__((ext_vector_type(4)));

__device__ inline uint16_t f2bf(float f) {
  uint32_t u = __float_as_uint(f);
  u += 0x7fffu + ((u >> 16) & 1u);
  return (uint16_t)(u >> 16);
}

__device__ inline void gload_lds16(const void* g, void* l) {
  __builtin_amdgcn_global_load_lds(
      (const __attribute__((address_space(1))) void*)g,
      (__attribute__((address_space(3))) void*)l, 16, 0, 0);
}

__device__ inline uint32_t cvtpk_bf16(float lo, float hi) {
  uint32_t r;
  asm("v_cvt_pk_bf16_f32 %0, %1, %2" : "=v"(r) : "v"(lo), "v"(hi));
  return r;
}
// in-place: a <- {a.lo, b.lo}, b <- {a.hi, b.hi}
__device__ inline void pl32swap(uint32_t& a, uint32_t& b) {
  asm("v_permlane32_swap_b32 %0, %1" : "+v"(a), "+v"(b));
}
}  // namespace

// ------------- fused cast f32 -> bf16 for x and kv -------------
__global__ __launch_bounds__(256) void cast_both_kernel(
    const float* __restrict__ x, const float* __restrict__ kv,
    uint16_t* __restrict__ xb, uint16_t* __restrict__ kvb, int nel) {
  int i = (blockIdx.x * 256 + threadIdx.x) * 4;
  const float* in;
  uint16_t* out;
  if (i < nel) { in = x + i; out = xb + i; }
  else         { in = kv + (i - nel); out = kvb + (i - nel); }
  const float4 v = *(const float4*)in;
  ushort4 o;
  o.x = f2bf(v.x); o.y = f2bf(v.y); o.z = f2bf(v.z); o.w = f2bf(v.w);
  *(ushort4*)out = o;
}

// ------------- fused transpose+cast of all 4 weights into [5120][2048] ----
// rows 0..2047: WqT, 2048..2559: WkT, 2560..3071: WvT, 3072..5119: WoT
__global__ __launch_bounds__(256) void transpose_all_kernel(
    const float* __restrict__ Wq, const float* __restrict__ Wk,
    const float* __restrict__ Wv, const float* __restrict__ Wo,
    uint16_t* __restrict__ out) {
  __shared__ uint16_t tile[32][33];
  const int gn0 = blockIdx.x * 32;  // output row block (0..5119)
  const int k0 = blockIdx.y * 32;
  const float* in;
  int Nr, start;
  if (gn0 < 2048)      { in = Wq; Nr = 2048; start = 0; }
  else if (gn0 < 2560) { in = Wk; Nr = 512;  start = 2048; }
  else if (gn0 < 3072) { in = Wv; Nr = 512;  start = 2560; }
  else                 { in = Wo; Nr = 2048; start = 3072; }
  const int n0 = gn0 - start;
  const int tx = threadIdx.x & 31, tg = threadIdx.x >> 5;
#pragma unroll
  for (int rr = 0; rr < 4; ++rr) {
    int k = tg * 4 + rr;
    tile[k][tx] = f2bf(in[(size_t)(k0 + k) * Nr + n0 + tx]);
  }
  __syncthreads();
#pragma unroll
  for (int rr = 0; rr < 4; ++rr) {
    int n = tg * 4 + rr;
    out[(size_t)(gn0 + n) * CD + k0 + tx] = tile[tx][n];
  }
}

// ------------- fused QKV projection GEMM (R5 config: best measured) ------
// 128x128 tile, BK=32, 256 thr / 4 waves, triple-buffered LDS (48 KiB ->
// 3 blocks/CU), counted vmcnt (never 0 in loop).
// C[4096, 3072] = A_sel[M,K] * WT[3072,K]^T + bias_sel ; region by n0:
//   n in [0,2048):    A=xb,  bias=bq, out Q[B,H,S,HD] scaled by 1/8*log2e
//   n in [2048,2560): A=kvb, bias=bk, out K[B,G,S,HD]
//   n in [2560,3072): A=kvb, bias=bv, out VT[B,G,HD,S]
__global__ __launch_bounds__(256, 2) void gemm_qkv_kernel(
    const uint16_t* __restrict__ xb, const uint16_t* __restrict__ kvb,
    const uint16_t* __restrict__ WT,
    const float* __restrict__ bq, const float* __restrict__ bk,
    const float* __restrict__ bv,
    uint16_t* __restrict__ Qb, uint16_t* __restrict__ Kb,
    uint16_t* __restrict__ VTb) {
  constexpr int BM = 128, BN = 128, BK = 32, K = 2048, NT = K / BK;  // 64
  constexpr int ASZ = BM * BK;       // 4096 elems
  constexpr int BSZ = BN * BK;       // 4096 elems
  constexpr int BUFSZ = ASZ + BSZ;   // 16 KB per K-tile
  __shared__ uint16_t smem[3 * BUFSZ];  // 48 KB -> 3 blocks/CU
  const int tid = threadIdx.x;
  const int w = tid >> 6, l = tid & 63;
  const int wr = w >> 1, wc = w & 1;   // 2M x 2N waves; per-wave 64x64
  const int l15 = l & 15, lq = l >> 4;

  // XCD-aware bijective swizzle (nwg = 768, divisible by 8)
  const int gx = gridDim.x;  // 24
  int bid = blockIdx.y * gx + blockIdx.x;
  const int nwg = gx * gridDim.y;
  bid = (bid & 7) * (nwg >> 3) + (bid >> 3);
  const int m0 = (bid / gx) * BM, n0 = (bid % gx) * BN;
  const uint16_t* A = (n0 < 2048) ? xb : kvb;

  // conflict-free swizzle for 64B rows: kq = slot ^ ((row>>1)&3)
  // (verified 0 bank conflicts); same involution on stage-src and ds_read.
  auto stage = [&](int buf, int kt) {
    uint16_t* base = smem + buf * BUFSZ;
    const int k0 = kt * BK;
#pragma unroll
    for (int i = 0; i < 2; ++i) {
      int g = i * 256 + tid;            // A granules 0..511 (128 rows x 4)
      int row = g >> 2, slot = g & 3;
      int kq = slot ^ ((row >> 1) & 3);
      gload_lds16(A + (size_t)(m0 + row) * K + k0 + kq * 8, base + g * 8);
    }
#pragma unroll
    for (int i = 0; i < 2; ++i) {
      int g = i * 256 + tid;            // B granules
      int row = g >> 2, slot = g & 3;
      int kq = slot ^ ((row >> 1) & 3);
      gload_lds16(WT + (size_t)(n0 + row) * K + k0 + kq * 8,
                  base + ASZ + g * 8);
    }
  };

  // swizzled LDS read byte-offsets (tile-invariant)
  int aOff[4], bOff[4];
#pragma unroll
  for (int m = 0; m < 4; ++m) {
    int row = wr * 64 + m * 16 + l15;
    aOff[m] = (row * BK + (lq ^ ((row >> 1) & 3)) * 8) * 2;
  }
#pragma unroll
  for (int n = 0; n < 4; ++n) {
    int row = wc * 64 + n * 16 + l15;
    bOff[n] = ASZ * 2 + (row * BK + (lq ^ ((row >> 1) & 3)) * 8) * 2;
  }

  f32x4 acc[4][4] = {};

  stage(0, 0);
  stage(1, 1);

  int bt = 0, bs = 2;  // compute buffer (t%3), stage buffer ((t+2)%3)
  for (int t = 0; t < NT; ++t) {
    // tile t landed when <= (loads of tile t+1 = 4) remain outstanding
    if (t < NT - 1) asm volatile("s_waitcnt vmcnt(4)" ::: "memory");
    else            asm volatile("s_waitcnt vmcnt(0)" ::: "memory");
    __builtin_amdgcn_s_barrier();
    asm volatile("" ::: "memory");

    const char* buf = (const char*)(smem + bt * BUFSZ);
    bf16x8 af[4], bfr[4];
#pragma unroll
    for (int m = 0; m < 4; ++m) af[m] = *(const bf16x8*)(buf + aOff[m]);
#pragma unroll
    for (int n = 0; n < 4; ++n) bfr[n] = *(const bf16x8*)(buf + bOff[n]);

    if (t + 2 < NT) stage(bs, t + 2);  // buffer of t-1: dead past the barrier

    __builtin_amdgcn_s_setprio(1);
#pragma unroll
    for (int m = 0; m < 4; ++m)
#pragma unroll
      for (int n = 0; n < 4; ++n)
        acc[m][n] = __builtin_amdgcn_mfma_f32_16x16x32_bf16(
            af[m], bfr[n], acc[m][n], 0, 0, 0);
    __builtin_amdgcn_s_setprio(0);

    bt = bt == 2 ? 0 : bt + 1;
    bs = bs == 2 ? 0 : bs + 1;
  }

#pragma unroll
  for (int m = 0; m < 4; ++m)
#pragma unroll
    for (int n = 0; n < 4; ++n)
#pragma unroll
      for (int r = 0; r < 4; ++r) {
        int gm = m0 + wr * 64 + m * 16 + lq * 4 + r;
        int gn = n0 + wc * 64 + n * 16 + l15;
        int b = gm >> 11, s = gm & (CS - 1);
        if (n0 < 2048) {  // Q (pre-scaled)
          float v = (acc[m][n][r] + bq[gn]) * (0.125f * 1.44269504088896340736f);
          int h = gn >> 6, hd = gn & 63;
          Qb[(((size_t)(b * CH + h)) * CS + s) * CHD + hd] = f2bf(v);
        } else if (n0 < 2560) {  // K
          int gn2 = gn - 2048;
          float v = acc[m][n][r] + bk[gn2];
          int gh = gn2 >> 6, hd = gn2 & 63;
          Kb[(((size_t)(b * CG + gh)) * CS + s) * CHD + hd] = f2bf(v);
        } else {  // V -> VT[B,G,HD,S]
          int gn2 = gn - 2560;
          float v = acc[m][n][r] + bv[gn2];
          int gh = gn2 >> 6, hd = gn2 & 63;
          VTb[(((size_t)(b * CG + gh)) * CHD + hd) * CS + s] = f2bf(v);
        }
      }
}

// ------------- output projection GEMM (R5 config) ------------------------
__global__ __launch_bounds__(256, 2) void gemm_out_kernel(
    const uint16_t* __restrict__ A, const uint16_t* __restrict__ Bt,
    const float* __restrict__ bias, float* __restrict__ Cout,
    int M, int N, int Kdim) {
  constexpr int BM = 128, BN = 128, BK = 32, K = 2048, NT = K / BK;  // 64
  constexpr int ASZ = BM * BK;       // 4096 elems
  constexpr int BSZ = BN * BK;       // 4096 elems
  constexpr int BUFSZ = ASZ + BSZ;   // 16 KB per K-tile
  __shared__ uint16_t smem[3 * BUFSZ];  // 48 KB
  const int tid = threadIdx.x;
  const int w = tid >> 6, l = tid & 63;
  const int wr = w >> 1, wc = w & 1;   // per-wave 64x64
  const int l15 = l & 15, lq = l >> 4;

  // XCD-aware bijective swizzle (nwg = 512, divisible by 8)
  const int gx = gridDim.x;  // 16
  int bid = blockIdx.y * gx + blockIdx.x;
  const int nwg = gx * gridDim.y;
  bid = (bid & 7) * (nwg >> 3) + (bid >> 3);
  const int m0 = (bid / gx) * BM, n0 = (bid % gx) * BN;

  auto stage = [&](int buf, int kt) {
    uint16_t* base = smem + buf * BUFSZ;
    const int k0 = kt * BK;
#pragma unroll
    for (int i = 0; i < 2; ++i) {
      int g = i * 256 + tid;
      int row = g >> 2, slot = g & 3;
      int kq = slot ^ ((row >> 1) & 3);
      gload_lds16(A + (size_t)(m0 + row) * K + k0 + kq * 8, base + g * 8);
    }
#pragma unroll
    for (int i = 0; i < 2; ++i) {
      int g = i * 256 + tid;
      int row = g >> 2, slot = g & 3;
      int kq = slot ^ ((row >> 1) & 3);
      gload_lds16(Bt + (size_t)(n0 + row) * K + k0 + kq * 8,
                  base + ASZ + g * 8);
    }
  };

  int aOff[4], bOff[4];
#pragma unroll
  for (int m = 0; m < 4; ++m) {
    int row = wr * 64 + m * 16 + l15;
    aOff[m] = (row * BK + (lq ^ ((row >> 1) & 3)) * 8) * 2;
  }
#pragma unroll
  for (int n = 0; n < 4; ++n) {
    int row = wc * 64 + n * 16 + l15;
    bOff[n] = ASZ * 2 + (row * BK + (lq ^ ((row >> 1) & 3)) * 8) * 2;
  }

  f32x4 acc[4][4] = {};

  stage(0, 0);
  stage(1, 1);

  int bt = 0, bs = 2;
  for (int t = 0; t < NT; ++t) {
    if (t < NT - 1) asm volatile("s_waitcnt vmcnt(4)" ::: "memory");
    else            asm volatile("s_waitcnt vmcnt(0)" ::: "memory");
    __builtin_amdgcn_s_barrier();
    asm volatile("" ::: "memory");

    const char* buf = (const char*)(smem + bt * BUFSZ);
    bf16x8 af[4], bfr[4];
#pragma unroll
    for (int m = 0; m < 4; ++m) af[m] = *(const bf16x8*)(buf + aOff[m]);
#pragma unroll
    for (int n = 0; n < 4; ++n) bfr[n] = *(const bf16x8*)(buf + bOff[n]);

    if (t + 2 < NT) stage(bs, t + 2);

    __builtin_amdgcn_s_setprio(1);
#pragma unroll
    for (int m = 0; m < 4; ++m)
#pragma unroll
      for (int n = 0; n < 4; ++n)
        acc[m][n] = __builtin_amdgcn_mfma_f32_16x16x32_bf16(
            af[m], bfr[n], acc[m][n], 0, 0, 0);
    __builtin_amdgcn_s_setprio(0);

    bt = bt == 2 ? 0 : bt + 1;
    bs = bs == 2 ? 0 : bs + 1;
  }

#pragma unroll
  for (int m = 0; m < 4; ++m)
#pragma unroll
    for (int n = 0; n < 4; ++n)
#pragma unroll
      for (int r = 0; r < 4; ++r) {
        int gm = m0 + wr * 64 + m * 16 + lq * 4 + r;
        int gn = n0 + wc * 64 + n * 16 + l15;
        Cout[(size_t)gm * N + gn] = acc[m][n][r] + bias[gn];
      }
}

// ---------------- causal flash attention, balanced pairs, KVBLK=128 ------
// Each block processes q-blocks {NQB-1-x, x} (128 rows each) => EQUAL work:
// nt = qb+1 K/V tiles of 128 keys -> (16-x) + (x+1) = 17 steps/block.
// Half the barriers/reductions/mask passes of KVBLK=64. 2-buffer drain
// (64 KiB LDS -> 2 blocks/CU, grid 512 = exactly 2/CU).
// Q[B,H,S,HD] bf16 (pre-scaled), K[B,G,S,HD] bf16, VT[B,G,HD,S] bf16
__global__ __launch_bounds__(256, 2) void flash_attn_kernel(
    const uint16_t* __restrict__ Q, const uint16_t* __restrict__ K,
    const uint16_t* __restrict__ VT, uint16_t* __restrict__ Aout) {
  constexpr int NQB = CS / 128;  // 16
  constexpr int KV = 128;        // keys per tile
  __shared__ __align__(16) uint16_t Ksm[2][KV * CHD];  // [key][hd] 16KB each
  __shared__ __align__(16) uint16_t Vsm[2][CHD * KV];  // [hd][key] 16KB each
  const int tid = threadIdx.x, w = tid >> 6, l = tid & 63;
  const int l31 = l & 31, hi = l >> 5;
  const int x = blockIdx.x;  // 0..NQB/2-1
  const int h = blockIdx.y, b = blockIdx.z, g = h >> 2;

  const uint16_t* Qbase = Q + ((size_t)(b * CH + h)) * CS * CHD;
  const uint16_t* Kbase = K + ((size_t)(b * CG + g)) * CS * CHD;
  const uint16_t* Vbase = VT + ((size_t)(b * CG + g)) * CHD * CS;

  // stage one K/V tile: K = 128 keys x 64 hd (128B rows, 8-slot XOR);
  // V = 64 hd x 128 keys (256B rows, 16-slot XOR). 4+4 granules/thread.
  auto stage = [&](int buf, int kt) {
#pragma unroll
    for (int i = 0; i < 4; ++i) {
      int gK = i * 256 + tid;           // 1024 granules, row=key, 8/row
      int rowK = gK >> 3, slotK = gK & 7;
      int kqK = slotK ^ (rowK & 7);
      gload_lds16(Kbase + ((size_t)kt * KV + rowK) * CHD + kqK * 8,
                  &Ksm[buf][gK * 8]);
    }
#pragma unroll
    for (int i = 0; i < 4; ++i) {
      int gV = i * 256 + tid;           // 1024 granules, row=hd, 16/row
      int rowV = gV >> 4, slotV = gV & 15;
      int kqV = slotV ^ (rowV & 15);
      gload_lds16(Vbase + (size_t)rowV * CS + kt * KV + kqV * 8,
                  &Vsm[buf][gV * 8]);
    }
  };

  // swizzled LDS read byte-offsets (kt-invariant)
  int kOff[4][4];   // K: row = c*32+l31 (key chunk c), col = kc*16+hi*8
#pragma unroll
  for (int c = 0; c < 4; ++c)
#pragma unroll
    for (int kc = 0; kc < 4; ++kc) {
      int row = c * 32 + l31;
      kOff[c][kc] = ((row * CHD + kc * 16 + hi * 8) * 2) ^ ((row & 7) << 4);
    }
  int vOff[2][8];   // V: row = c*32+l31 (hd half c), col = ks*16+hi*8
#pragma unroll
  for (int c = 0; c < 2; ++c)
#pragma unroll
    for (int ks = 0; ks < 8; ++ks) {
      int row = c * 32 + l31;
      vOff[c][ks] = ((row * KV + ks * 16 + hi * 8) * 2) ^ ((row & 15) << 4);
    }

#pragma unroll 1
  for (int job = 0; job < 2; ++job) {
    const int qb = job == 0 ? (NQB - 1 - x) : x;
    const int qrow = qb * 128 + w * 32 + l31;
    const int wbase = qb * 128 + w * 32;  // wave's FIRST q-row

    // Q B-frags: qf[kc] elem j = Q[qrow][kc*16 + hi*8 + j]
    bf16x8 qf[4];
#pragma unroll
    for (int kc = 0; kc < 4; ++kc)
      qf[kc] = *(const bf16x8*)(Qbase + (size_t)qrow * CHD + kc * 16 + hi * 8);

    f32x16 o0 = {}, o1 = {};
    float mrun = -3e38f, lrun = 0.f;
    const int nt = qb + 1;

    stage(0, 0);
    asm volatile("s_waitcnt vmcnt(0)" ::: "memory");
    __syncthreads();

    for (int kt = 0; kt < nt; ++kt) {
      const int cur = kt & 1;
      if (kt + 1 < nt) stage(cur ^ 1, kt + 1);

      const char* ksmb = (const char*)Ksm[cur];
      const char* vsmb = (const char*)Vsm[cur];

      // swapped QK^T: p[c] = K_chunk_c * Q -> P[key=32c+crow][q=l31]
      f32x16 p0 = {}, p1 = {}, p2 = {}, p3 = {};
      __builtin_amdgcn_s_setprio(1);
#pragma unroll
      for (int kc = 0; kc < 4; ++kc) {
        bf16x8 ka0 = *(const bf16x8*)(ksmb + kOff[0][kc]);
        bf16x8 ka1 = *(const bf16x8*)(ksmb + kOff[1][kc]);
        bf16x8 ka2 = *(const bf16x8*)(ksmb + kOff[2][kc]);
        bf16x8 ka3 = *(const bf16x8*)(ksmb + kOff[3][kc]);
        p0 = __builtin_amdgcn_mfma_f32_32x32x16_bf16(ka0, qf[kc], p0, 0, 0, 0);
        p1 = __builtin_amdgcn_mfma_f32_32x32x16_bf16(ka1, qf[kc], p1, 0, 0, 0);
        p2 = __builtin_amdgcn_mfma_f32_32x32x16_bf16(ka2, qf[kc], p2, 0, 0, 0);
        p3 = __builtin_amdgcn_mfma_f32_32x32x16_bf16(ka3, qf[kc], p3, 0, 0, 0);
      }
      __builtin_amdgcn_s_setprio(0);

      // causal mask: needed when tile's last key exceeds wave's FIRST row
      // (per-lane loop masks exactly; R10 bug compared against last row).
      const bool need_mask = (kt * KV + KV - 1 > wbase);
      if (need_mask) {
#pragma unroll
        for (int r = 0; r < 16; ++r) {
          int keyb = kt * KV + (r & 3) + 8 * (r >> 2) + 4 * hi;
          if (keyb > qrow) p0[r] = -3e38f;
          if (keyb + 32 > qrow) p1[r] = -3e38f;
          if (keyb + 64 > qrow) p2[r] = -3e38f;
          if (keyb + 96 > qrow) p3[r] = -3e38f;
        }
      }
      float pmax = -3e38f;
#pragma unroll
      for (int r = 0; r < 16; ++r) {
        pmax = fmaxf(pmax, fmaxf(fmaxf(p0[r], p1[r]), fmaxf(p2[r], p3[r])));
      }
      pmax = fmaxf(pmax, __shfl_xor(pmax, 32));

      // defer-max: skip O-rescale unless max grew past threshold
      if (!__all(pmax <= mrun + 8.f)) {
        float mnew = fmaxf(mrun, pmax);
        float alpha = __builtin_amdgcn_exp2f(mrun - mnew);
#pragma unroll
        for (int r = 0; r < 16; ++r) { o0[r] *= alpha; o1[r] *= alpha; }
        lrun *= alpha;
        mrun = mnew;
      }
      float s = 0.f;
#pragma unroll
      for (int r = 0; r < 16; ++r) {
        float e0 = __builtin_amdgcn_exp2f(p0[r] - mrun);
        float e1 = __builtin_amdgcn_exp2f(p1[r] - mrun);
        float e2 = __builtin_amdgcn_exp2f(p2[r] - mrun);
        float e3 = __builtin_amdgcn_exp2f(p3[r] - mrun);
        p0[r] = e0; p1[r] = e1; p2[r] = e2; p3[r] = e3;
        s += (e0 + e1) + (e2 + e3);
      }
      s += __shfl_xor(s, 32);
      lrun += s;

      // P -> bf16 B-frags in-register (cvt_pk + permlane32_swap)
      u32x4 paw[8];
#pragma unroll
      for (int k = 0; k < 8; ++k) {
        const int base = (k & 1) * 8;
        const int c = k >> 1;
        const f32x16& pc = (c == 0) ? p0 : (c == 1) ? p1 : (c == 2) ? p2 : p3;
        uint32_t c01 = cvtpk_bf16(pc[base + 0], pc[base + 1]);
        uint32_t c23 = cvtpk_bf16(pc[base + 2], pc[base + 3]);
        uint32_t c45 = cvtpk_bf16(pc[base + 4], pc[base + 5]);
        uint32_t c67 = cvtpk_bf16(pc[base + 6], pc[base + 7]);
        pl32swap(c01, c45);
        pl32swap(c23, c67);
        paw[k] = (u32x4){c01, c23, c45, c67};
      }

      // PV (swapped): o[hc] += V^T_chunk * P, summed over 8 key-slices
      __builtin_amdgcn_s_setprio(1);
#pragma unroll
      for (int ks = 0; ks < 8; ++ks) {
        bf16x8 vb0 = *(const bf16x8*)(vsmb + vOff[0][ks]);
        bf16x8 vb1 = *(const bf16x8*)(vsmb + vOff[1][ks]);
        bf16x8 pb = __builtin_bit_cast(bf16x8, paw[ks]);
        o0 = __builtin_amdgcn_mfma_f32_32x32x16_bf16(vb0, pb, o0, 0, 0, 0);
        o1 = __builtin_amdgcn_mfma_f32_32x32x16_bf16(vb1, pb, o1, 0, 0, 0);
      }
      __builtin_amdgcn_s_setprio(0);

      asm volatile("s_waitcnt vmcnt(0)" ::: "memory");
      __syncthreads();
    }

    // epilogue: lane owns q-row qrow; cols hd = crow(reg,hi)+32*hc
    float invl = 1.f / lrun;
    uint16_t* orow = Aout + ((size_t)b * CS + qrow) * CD + (size_t)h * CHD;
#pragma unroll
    for (int k = 0; k < 8; ++k) {
      int reg = 2 * k;
      int hd = (reg & 3) + 8 * (reg >> 2) + 4 * hi;
      *(uint32_t*)(orow + hd) = cvtpk_bf16(o0[reg] * invl, o0[reg + 1] * invl);
      *(uint32_t*)(orow + hd + 32) = cvtpk_bf16(o1[reg] * invl, o1[reg + 1] * invl);
    }
  }
}

extern "C" void kernel_launch(void* const* d_in, const int* in_sizes, int n_in,
                              void* d_out, int out_size, void* d_ws, size_t ws_size,
                              hipStream_t stream) {
  const float* x = (const float*)d_in[0];
  const float* kv = (const float*)d_in[1];
  const float* Wq = (const float*)d_in[2];
  const float* bq = (const float*)d_in[3];
  const float* Wk = (const float*)d_in[4];
  const float* bk = (const float*)d_in[5];
  const float* Wv = (const float*)d_in[6];
  const float* bv = (const float*)d_in[7];
  const float* Wo = (const float*)d_in[8];
  const float* bo = (const float*)d_in[9];
  float* out = (float*)d_out;

  char* ws = (char*)d_ws;
  uint16_t* xb = (uint16_t*)ws;   ws += (size_t)CB * CS * CD * 2;
  uint16_t* kvb = (uint16_t*)ws;  ws += (size_t)CB * CS * CD * 2;
  uint16_t* WqT = (uint16_t*)ws;  ws += (size_t)CD * CD * 2;        // rows 0..2047
  uint16_t* WkT = (uint16_t*)ws;  ws += (size_t)(CG * CHD) * CD * 2;  // 2048..2559
  uint16_t* WvT = (uint16_t*)ws;  ws += (size_t)(CG * CHD) * CD * 2;  // 2560..3071
  uint16_t* WoT = (uint16_t*)ws;  ws += (size_t)CD * CD * 2;        // 3072..5119
  uint16_t* Qb = (uint16_t*)ws;   ws += (size_t)CB * CH * CS * CHD * 2;
  uint16_t* Kb = (uint16_t*)ws;   ws += (size_t)CB * CG * CS * CHD * 2;
  uint16_t* VTb = (uint16_t*)ws;  ws += (size_t)CB * CG * CHD * CS * 2;
  uint16_t* attnb = (uint16_t*)ws;
  (void)WkT; (void)WvT;

  const int NTOK = CB * CS;  // 4096
  const int nel = CB * CS * CD;

  cast_both_kernel<<<2 * nel / 4 / 256, 256, 0, stream>>>(x, kv, xb, kvb, nel);
  transpose_all_kernel<<<dim3(5120 / 32, CD / 32), 256, 0, stream>>>(
      Wq, Wk, Wv, Wo, WqT);

  gemm_qkv_kernel<<<dim3(3072 / 128, NTOK / 128), 256, 0, stream>>>(
      xb, kvb, WqT, bq, bk, bv, Qb, Kb, VTb);

  flash_attn_kernel<<<dim3(CS / 256, CH, CB), 256, 0, stream>>>(Qb, Kb, VTb, attnb);

  gemm_out_kernel<<<dim3(CD / 128, NTOK / 128), 256, 0, stream>>>(
      attnb, WoT, bo, out, NTOK, CD, CD);
}

// Round 12
// 200.005 us; speedup vs baseline: 1.2695x; 1.0032x over previous
//
#include <hip/hip_runtime.h>
#include <hip/hip_bf16.h>
#include <stdint.h>

namespace {
constexpr int CB = 2, CS = 2048, CD = 2048, CH = 32, CG = 8, CHD = 64, CGS = 4;

typedef __bf16 bf16x8 __attribute__((ext_vector_type(8)));
typedef float f32x4 __attribute__((ext_vector_type(4)));
typedef float f32x16 __attribute__((ext_vector_type(16)));
typedef uint32_t u32x4 __attribute__((ext_vector_type(4)));

__device__ inline uint16_t f2bf(float f) {
  uint32_t u = __float_as_uint(f);
  u += 0x7fffu + ((u >> 16) & 1u);
  return (uint16_t)(u >> 16);
}

__device__ inline void gload_lds16(const void* g, void* l) {
  __builtin_amdgcn_global_load_lds(
      (const __attribute__((address_space(1))) void*)g,
      (__attribute__((address_space(3))) void*)l, 16, 0, 0);
}

__device__ inline uint32_t cvtpk_bf16(float lo, float hi) {
  uint32_t r;
  asm("v_cvt_pk_bf16_f32 %0, %1, %2" : "=v"(r) : "v"(lo), "v"(hi));
  return r;
}
// in-place: a <- {a.lo, b.lo}, b <- {a.hi, b.hi}
__device__ inline void pl32swap(uint32_t& a, uint32_t& b) {
  asm("v_permlane32_swap_b32 %0, %1" : "+v"(a), "+v"(b));
}
}  // namespace

// ------------- fused cast f32 -> bf16 for x and kv -------------
__global__ __launch_bounds__(256) void cast_both_kernel(
    const float* __restrict__ x, const float* __restrict__ kv,
    uint16_t* __restrict__ xb, uint16_t* __restrict__ kvb, int nel) {
  int i = (blockIdx.x * 256 + threadIdx.x) * 4;
  const float* in;
  uint16_t* out;
  if (i < nel) { in = x + i; out = xb + i; }
  else         { in = kv + (i - nel); out = kvb + (i - nel); }
  const float4 v = *(const float4*)in;
  ushort4 o;
  o.x = f2bf(v.x); o.y = f2bf(v.y); o.z = f2bf(v.z); o.w = f2bf(v.w);
  *(ushort4*)out = o;
}

// ------------- fused transpose+cast of all 4 weights into [5120][2048] ----
// rows 0..2047: WqT, 2048..2559: WkT, 2560..3071: WvT, 3072..5119: WoT
__global__ __launch_bounds__(256) void transpose_all_kernel(
    const float* __restrict__ Wq, const float* __restrict__ Wk,
    const float* __restrict__ Wv, const float* __restrict__ Wo,
    uint16_t* __restrict__ out) {
  __shared__ uint16_t tile[32][33];
  const int gn0 = blockIdx.x * 32;  // output row block (0..5119)
  const int k0 = blockIdx.y * 32;
  const float* in;
  int Nr, start;
  if (gn0 < 2048)      { in = Wq; Nr = 2048; start = 0; }
  else if (gn0 < 2560) { in = Wk; Nr = 512;  start = 2048; }
  else if (gn0 < 3072) { in = Wv; Nr = 512;  start = 2560; }
  else                 { in = Wo; Nr = 2048; start = 3072; }
  const int n0 = gn0 - start;
  const int tx = threadIdx.x & 31, tg = threadIdx.x >> 5;
#pragma unroll
  for (int rr = 0; rr < 4; ++rr) {
    int k = tg * 4 + rr;
    tile[k][tx] = f2bf(in[(size_t)(k0 + k) * Nr + n0 + tx]);
  }
  __syncthreads();
#pragma unroll
  for (int rr = 0; rr < 4; ++rr) {
    int n = tg * 4 + rr;
    out[(size_t)(gn0 + n) * CD + k0 + tx] = tile[tx][n];
  }
}

// ------------- fused QKV projection GEMM (8-wave 128², 3-buf counted) ----
// 128x128 tile, BK=32, 512 thr / 8 waves (2M x 4N, per-wave 64x32),
// triple-buffered LDS (48 KiB -> 3 blocks/CU = 24 waves/CU), counted vmcnt.
// Same skeleton/swizzle as the verified R5 config; only wave decomposition
// differs (12 -> 24 waves/CU for latency hiding).
// C[4096, 3072] = A_sel[M,K] * WT[3072,K]^T + bias_sel ; region by n0:
//   n in [0,2048):    A=xb,  bias=bq, out Q[B,H,S,HD] scaled by 1/8*log2e
//   n in [2048,2560): A=kvb, bias=bk, out K[B,G,S,HD]
//   n in [2560,3072): A=kvb, bias=bv, out VT[B,G,HD,S]
__global__ __launch_bounds__(512, 6) void gemm_qkv_kernel(
    const uint16_t* __restrict__ xb, const uint16_t* __restrict__ kvb,
    const uint16_t* __restrict__ WT,
    const float* __restrict__ bq, const float* __restrict__ bk,
    const float* __restrict__ bv,
    uint16_t* __restrict__ Qb, uint16_t* __restrict__ Kb,
    uint16_t* __restrict__ VTb) {
  constexpr int BM = 128, BN = 128, BK = 32, K = 2048, NT = K / BK;  // 64
  constexpr int ASZ = BM * BK;       // 4096 elems
  constexpr int BSZ = BN * BK;       // 4096 elems
  constexpr int BUFSZ = ASZ + BSZ;   // 16 KB per K-tile
  __shared__ uint16_t smem[3 * BUFSZ];  // 48 KB -> 3 blocks/CU
  const int tid = threadIdx.x;
  const int w = tid >> 6, l = tid & 63;
  const int wr = w >> 2, wc = w & 3;   // 2M x 4N waves; per-wave 64x32
  const int l15 = l & 15, lq = l >> 4;

  // XCD-aware bijective swizzle (nwg = 768, divisible by 8)
  const int gx = gridDim.x;  // 24
  int bid = blockIdx.y * gx + blockIdx.x;
  const int nwg = gx * gridDim.y;
  bid = (bid & 7) * (nwg >> 3) + (bid >> 3);
  const int m0 = (bid / gx) * BM, n0 = (bid % gx) * BN;
  const uint16_t* A = (n0 < 2048) ? xb : kvb;

  // conflict-free swizzle for 64B rows: kq = slot ^ ((row>>1)&3)
  // (verified 0 bank conflicts); same involution on stage-src and ds_read.
  // 512 threads: 1 A granule + 1 B granule per thread per tile.
  auto stage = [&](int buf, int kt) {
    uint16_t* base = smem + buf * BUFSZ;
    const int k0 = kt * BK;
    {
      int g = tid;                      // A granules 0..511 (128 rows x 4)
      int row = g >> 2, slot = g & 3;
      int kq = slot ^ ((row >> 1) & 3);
      gload_lds16(A + (size_t)(m0 + row) * K + k0 + kq * 8, base + g * 8);
    }
    {
      int g = tid;                      // B granules
      int row = g >> 2, slot = g & 3;
      int kq = slot ^ ((row >> 1) & 3);
      gload_lds16(WT + (size_t)(n0 + row) * K + k0 + kq * 8,
                  base + ASZ + g * 8);
    }
  };

  // swizzled LDS read byte-offsets (tile-invariant)
  int aOff[4], bOff[2];
#pragma unroll
  for (int m = 0; m < 4; ++m) {
    int row = wr * 64 + m * 16 + l15;
    aOff[m] = (row * BK + (lq ^ ((row >> 1) & 3)) * 8) * 2;
  }
#pragma unroll
  for (int n = 0; n < 2; ++n) {
    int row = wc * 32 + n * 16 + l15;
    bOff[n] = ASZ * 2 + (row * BK + (lq ^ ((row >> 1) & 3)) * 8) * 2;
  }

  f32x4 acc[4][2] = {};

  stage(0, 0);
  stage(1, 1);

  int bt = 0, bs = 2;  // compute buffer (t%3), stage buffer ((t+2)%3)
  for (int t = 0; t < NT; ++t) {
    // tile t landed when <= (loads of tile t+1 = 2) remain outstanding
    if (t < NT - 1) asm volatile("s_waitcnt vmcnt(2)" ::: "memory");
    else            asm volatile("s_waitcnt vmcnt(0)" ::: "memory");
    __builtin_amdgcn_s_barrier();
    asm volatile("" ::: "memory");

    const char* buf = (const char*)(smem + bt * BUFSZ);
    bf16x8 af[4], bfr[2];
#pragma unroll
    for (int m = 0; m < 4; ++m) af[m] = *(const bf16x8*)(buf + aOff[m]);
#pragma unroll
    for (int n = 0; n < 2; ++n) bfr[n] = *(const bf16x8*)(buf + bOff[n]);

    if (t + 2 < NT) stage(bs, t + 2);  // buffer of t-1: dead past the barrier

    __builtin_amdgcn_s_setprio(1);
#pragma unroll
    for (int m = 0; m < 4; ++m)
#pragma unroll
      for (int n = 0; n < 2; ++n)
        acc[m][n] = __builtin_amdgcn_mfma_f32_16x16x32_bf16(
            af[m], bfr[n], acc[m][n], 0, 0, 0);
    __builtin_amdgcn_s_setprio(0);

    bt = bt == 2 ? 0 : bt + 1;
    bs = bs == 2 ? 0 : bs + 1;
  }

#pragma unroll
  for (int m = 0; m < 4; ++m)
#pragma unroll
    for (int n = 0; n < 2; ++n)
#pragma unroll
      for (int r = 0; r < 4; ++r) {
        int gm = m0 + wr * 64 + m * 16 + lq * 4 + r;
        int gn = n0 + wc * 32 + n * 16 + l15;
        int b = gm >> 11, s = gm & (CS - 1);
        if (n0 < 2048) {  // Q (pre-scaled)
          float v = (acc[m][n][r] + bq[gn]) * (0.125f * 1.44269504088896340736f);
          int h = gn >> 6, hd = gn & 63;
          Qb[(((size_t)(b * CH + h)) * CS + s) * CHD + hd] = f2bf(v);
        } else if (n0 < 2560) {  // K
          int gn2 = gn - 2048;
          float v = acc[m][n][r] + bk[gn2];
          int gh = gn2 >> 6, hd = gn2 & 63;
          Kb[(((size_t)(b * CG + gh)) * CS + s) * CHD + hd] = f2bf(v);
        } else {  // V -> VT[B,G,HD,S]
          int gn2 = gn - 2560;
          float v = acc[m][n][r] + bv[gn2];
          int gh = gn2 >> 6, hd = gn2 & 63;
          VTb[(((size_t)(b * CG + gh)) * CHD + hd) * CS + s] = f2bf(v);
        }
      }
}

// ------------- output projection GEMM (8-wave 128², 3-buf counted) -------
__global__ __launch_bounds__(512, 6) void gemm_out_kernel(
    const uint16_t* __restrict__ A, const uint16_t* __restrict__ Bt,
    const float* __restrict__ bias, float* __restrict__ Cout,
    int M, int N, int Kdim) {
  constexpr int BM = 128, BN = 128, BK = 32, K = 2048, NT = K / BK;  // 64
  constexpr int ASZ = BM * BK;       // 4096 elems
  constexpr int BSZ = BN * BK;       // 4096 elems
  constexpr int BUFSZ = ASZ + BSZ;   // 16 KB per K-tile
  __shared__ uint16_t smem[3 * BUFSZ];  // 48 KB
  const int tid = threadIdx.x;
  const int w = tid >> 6, l = tid & 63;
  const int wr = w >> 2, wc = w & 3;   // per-wave 64x32
  const int l15 = l & 15, lq = l >> 4;

  // XCD-aware bijective swizzle (nwg = 512, divisible by 8)
  const int gx = gridDim.x;  // 16
  int bid = blockIdx.y * gx + blockIdx.x;
  const int nwg = gx * gridDim.y;
  bid = (bid & 7) * (nwg >> 3) + (bid >> 3);
  const int m0 = (bid / gx) * BM, n0 = (bid % gx) * BN;

  auto stage = [&](int buf, int kt) {
    uint16_t* base = smem + buf * BUFSZ;
    const int k0 = kt * BK;
    {
      int g = tid;
      int row = g >> 2, slot = g & 3;
      int kq = slot ^ ((row >> 1) & 3);
      gload_lds16(A + (size_t)(m0 + row) * K + k0 + kq * 8, base + g * 8);
    }
    {
      int g = tid;
      int row = g >> 2, slot = g & 3;
      int kq = slot ^ ((row >> 1) & 3);
      gload_lds16(Bt + (size_t)(n0 + row) * K + k0 + kq * 8,
                  base + ASZ + g * 8);
    }
  };

  int aOff[4], bOff[2];
#pragma unroll
  for (int m = 0; m < 4; ++m) {
    int row = wr * 64 + m * 16 + l15;
    aOff[m] = (row * BK + (lq ^ ((row >> 1) & 3)) * 8) * 2;
  }
#pragma unroll
  for (int n = 0; n < 2; ++n) {
    int row = wc * 32 + n * 16 + l15;
    bOff[n] = ASZ * 2 + (row * BK + (lq ^ ((row >> 1) & 3)) * 8) * 2;
  }

  f32x4 acc[4][2] = {};

  stage(0, 0);
  stage(1, 1);

  int bt = 0, bs = 2;
  for (int t = 0; t < NT; ++t) {
    if (t < NT - 1) asm volatile("s_waitcnt vmcnt(2)" ::: "memory");
    else            asm volatile("s_waitcnt vmcnt(0)" ::: "memory");
    __builtin_amdgcn_s_barrier();
    asm volatile("" ::: "memory");

    const char* buf = (const char*)(smem + bt * BUFSZ);
    bf16x8 af[4], bfr[2];
#pragma unroll
    for (int m = 0; m < 4; ++m) af[m] = *(const bf16x8*)(buf + aOff[m]);
#pragma unroll
    for (int n = 0; n < 2; ++n) bfr[n] = *(const bf16x8*)(buf + bOff[n]);

    if (t + 2 < NT) stage(bs, t + 2);

    __builtin_amdgcn_s_setprio(1);
#pragma unroll
    for (int m = 0; m < 4; ++m)
#pragma unroll
      for (int n = 0; n < 2; ++n)
        acc[m][n] = __builtin_amdgcn_mfma_f32_16x16x32_bf16(
            af[m], bfr[n], acc[m][n], 0, 0, 0);
    __builtin_amdgcn_s_setprio(0);

    bt = bt == 2 ? 0 : bt + 1;
    bs = bs == 2 ? 0 : bs + 1;
  }

#pragma unroll
  for (int m = 0; m < 4; ++m)
#pragma unroll
    for (int n = 0; n < 2; ++n)
#pragma unroll
      for (int r = 0; r < 4; ++r) {
        int gm = m0 + wr * 64 + m * 16 + lq * 4 + r;
        int gn = n0 + wc * 32 + n * 16 + l15;
        Cout[(size_t)gm * N + gn] = acc[m][n][r] + bias[gn];
      }
}

// ---------------- causal flash attention, balanced pairs, KVBLK=128 ------
// Each block processes q-blocks {NQB-1-x, x} (128 rows each) => EQUAL work:
// nt = qb+1 K/V tiles of 128 keys -> (16-x) + (x+1) = 17 steps/block.
// 2-buffer drain (64 KiB LDS -> 2 blocks/CU, grid 512 = exactly 2/CU).
// Q[B,H,S,HD] bf16 (pre-scaled), K[B,G,S,HD] bf16, VT[B,G,HD,S] bf16
__global__ __launch_bounds__(256, 2) void flash_attn_kernel(
    const uint16_t* __restrict__ Q, const uint16_t* __restrict__ K,
    const uint16_t* __restrict__ VT, uint16_t* __restrict__ Aout) {
  constexpr int NQB = CS / 128;  // 16
  constexpr int KV = 128;        // keys per tile
  __shared__ __align__(16) uint16_t Ksm[2][KV * CHD];  // [key][hd] 16KB each
  __shared__ __align__(16) uint16_t Vsm[2][CHD * KV];  // [hd][key] 16KB each
  const int tid = threadIdx.x, w = tid >> 6, l = tid & 63;
  const int l31 = l & 31, hi = l >> 5;
  const int x = blockIdx.x;  // 0..NQB/2-1
  const int h = blockIdx.y, b = blockIdx.z, g = h >> 2;

  const uint16_t* Qbase = Q + ((size_t)(b * CH + h)) * CS * CHD;
  const uint16_t* Kbase = K + ((size_t)(b * CG + g)) * CS * CHD;
  const uint16_t* Vbase = VT + ((size_t)(b * CG + g)) * CHD * CS;

  // stage one K/V tile: K = 128 keys x 64 hd (128B rows, 8-slot XOR);
  // V = 64 hd x 128 keys (256B rows, 16-slot XOR). 4+4 granules/thread.
  auto stage = [&](int buf, int kt) {
#pragma unroll
    for (int i = 0; i < 4; ++i) {
      int gK = i * 256 + tid;           // 1024 granules, row=key, 8/row
      int rowK = gK >> 3, slotK = gK & 7;
      int kqK = slotK ^ (rowK & 7);
      gload_lds16(Kbase + ((size_t)kt * KV + rowK) * CHD + kqK * 8,
                  &Ksm[buf][gK * 8]);
    }
#pragma unroll
    for (int i = 0; i < 4; ++i) {
      int gV = i * 256 + tid;           // 1024 granules, row=hd, 16/row
      int rowV = gV >> 4, slotV = gV & 15;
      int kqV = slotV ^ (rowV & 15);
      gload_lds16(Vbase + (size_t)rowV * CS + kt * KV + kqV * 8,
                  &Vsm[buf][gV * 8]);
    }
  };

  // swizzled LDS read byte-offsets (kt-invariant)
  int kOff[4][4];   // K: row = c*32+l31 (key chunk c), col = kc*16+hi*8
#pragma unroll
  for (int c = 0; c < 4; ++c)
#pragma unroll
    for (int kc = 0; kc < 4; ++kc) {
      int row = c * 32 + l31;
      kOff[c][kc] = ((row * CHD + kc * 16 + hi * 8) * 2) ^ ((row & 7) << 4);
    }
  int vOff[2][8];   // V: row = c*32+l31 (hd half c), col = ks*16+hi*8
#pragma unroll
  for (int c = 0; c < 2; ++c)
#pragma unroll
    for (int ks = 0; ks < 8; ++ks) {
      int row = c * 32 + l31;
      vOff[c][ks] = ((row * KV + ks * 16 + hi * 8) * 2) ^ ((row & 15) << 4);
    }

#pragma unroll 1
  for (int job = 0; job < 2; ++job) {
    const int qb = job == 0 ? (NQB - 1 - x) : x;
    const int qrow = qb * 128 + w * 32 + l31;
    const int wbase = qb * 128 + w * 32;  // wave's FIRST q-row

    // Q B-frags: qf[kc] elem j = Q[qrow][kc*16 + hi*8 + j]
    bf16x8 qf[4];
#pragma unroll
    for (int kc = 0; kc < 4; ++kc)
      qf[kc] = *(const bf16x8*)(Qbase + (size_t)qrow * CHD + kc * 16 + hi * 8);

    f32x16 o0 = {}, o1 = {};
    float mrun = -3e38f, lrun = 0.f;
    const int nt = qb + 1;

    stage(0, 0);
    asm volatile("s_waitcnt vmcnt(0)" ::: "memory");
    __syncthreads();

    for (int kt = 0; kt < nt; ++kt) {
      const int cur = kt & 1;
      if (kt + 1 < nt) stage(cur ^ 1, kt + 1);

      const char* ksmb = (const char*)Ksm[cur];
      const char* vsmb = (const char*)Vsm[cur];

      // swapped QK^T: p[c] = K_chunk_c * Q -> P[key=32c+crow][q=l31]
      f32x16 p0 = {}, p1 = {}, p2 = {}, p3 = {};
      __builtin_amdgcn_s_setprio(1);
#pragma unroll
      for (int kc = 0; kc < 4; ++kc) {
        bf16x8 ka0 = *(const bf16x8*)(ksmb + kOff[0][kc]);
        bf16x8 ka1 = *(const bf16x8*)(ksmb + kOff[1][kc]);
        bf16x8 ka2 = *(const bf16x8*)(ksmb + kOff[2][kc]);
        bf16x8 ka3 = *(const bf16x8*)(ksmb + kOff[3][kc]);
        p0 = __builtin_amdgcn_mfma_f32_32x32x16_bf16(ka0, qf[kc], p0, 0, 0, 0);
        p1 = __builtin_amdgcn_mfma_f32_32x32x16_bf16(ka1, qf[kc], p1, 0, 0, 0);
        p2 = __builtin_amdgcn_mfma_f32_32x32x16_bf16(ka2, qf[kc], p2, 0, 0, 0);
        p3 = __builtin_amdgcn_mfma_f32_32x32x16_bf16(ka3, qf[kc], p3, 0, 0, 0);
      }
      __builtin_amdgcn_s_setprio(0);

      // causal mask: needed when tile's last key exceeds wave's FIRST row
      const bool need_mask = (kt * KV + KV - 1 > wbase);
      if (need_mask) {
#pragma unroll
        for (int r = 0; r < 16; ++r) {
          int keyb = kt * KV + (r & 3) + 8 * (r >> 2) + 4 * hi;
          if (keyb > qrow) p0[r] = -3e38f;
          if (keyb + 32 > qrow) p1[r] = -3e38f;
          if (keyb + 64 > qrow) p2[r] = -3e38f;
          if (keyb + 96 > qrow) p3[r] = -3e38f;
        }
      }
      float pmax = -3e38f;
#pragma unroll
      for (int r = 0; r < 16; ++r) {
        pmax = fmaxf(pmax, fmaxf(fmaxf(p0[r], p1[r]), fmaxf(p2[r], p3[r])));
      }
      pmax = fmaxf(pmax, __shfl_xor(pmax, 32));

      // defer-max: skip O-rescale unless max grew past threshold
      if (!__all(pmax <= mrun + 8.f)) {
        float mnew = fmaxf(mrun, pmax);
        float alpha = __builtin_amdgcn_exp2f(mrun - mnew);
#pragma unroll
        for (int r = 0; r < 16; ++r) { o0[r] *= alpha; o1[r] *= alpha; }
        lrun *= alpha;
        mrun = mnew;
      }
      float s = 0.f;
#pragma unroll
      for (int r = 0; r < 16; ++r) {
        float e0 = __builtin_amdgcn_exp2f(p0[r] - mrun);
        float e1 = __builtin_amdgcn_exp2f(p1[r] - mrun);
        float e2 = __builtin_amdgcn_exp2f(p2[r] - mrun);
        float e3 = __builtin_amdgcn_exp2f(p3[r] - mrun);
        p0[r] = e0; p1[r] = e1; p2[r] = e2; p3[r] = e3;
        s += (e0 + e1) + (e2 + e3);
      }
      s += __shfl_xor(s, 32);
      lrun += s;

      // P -> bf16 B-frags in-register (cvt_pk + permlane32_swap)
      u32x4 paw[8];
#pragma unroll
      for (int k = 0; k < 8; ++k) {
        const int base = (k & 1) * 8;
        const int c = k >> 1;
        const f32x16& pc = (c == 0) ? p0 : (c == 1) ? p1 : (c == 2) ? p2 : p3;
        uint32_t c01 = cvtpk_bf16(pc[base + 0], pc[base + 1]);
        uint32_t c23 = cvtpk_bf16(pc[base + 2], pc[base + 3]);
        uint32_t c45 = cvtpk_bf16(pc[base + 4], pc[base + 5]);
        uint32_t c67 = cvtpk_bf16(pc[base + 6], pc[base + 7]);
        pl32swap(c01, c45);
        pl32swap(c23, c67);
        paw[k] = (u32x4){c01, c23, c45, c67};
      }

      // PV (swapped): o[hc] += V^T_chunk * P, summed over 8 key-slices
      __builtin_amdgcn_s_setprio(1);
#pragma unroll
      for (int ks = 0; ks < 8; ++ks) {
        bf16x8 vb0 = *(const bf16x8*)(vsmb + vOff[0][ks]);
        bf16x8 vb1 = *(const bf16x8*)(vsmb + vOff[1][ks]);
        bf16x8 pb = __builtin_bit_cast(bf16x8, paw[ks]);
        o0 = __builtin_amdgcn_mfma_f32_32x32x16_bf16(vb0, pb, o0, 0, 0, 0);
        o1 = __builtin_amdgcn_mfma_f32_32x32x16_bf16(vb1, pb, o1, 0, 0, 0);
      }
      __builtin_amdgcn_s_setprio(0);

      asm volatile("s_waitcnt vmcnt(0)" ::: "memory");
      __syncthreads();
    }

    // epilogue: lane owns q-row qrow; cols hd = crow(reg,hi)+32*hc
    float invl = 1.f / lrun;
    uint16_t* orow = Aout + ((size_t)b * CS + qrow) * CD + (size_t)h * CHD;
#pragma unroll
    for (int k = 0; k < 8; ++k) {
      int reg = 2 * k;
      int hd = (reg & 3) + 8 * (reg >> 2) + 4 * hi;
      *(uint32_t*)(orow + hd) = cvtpk_bf16(o0[reg] * invl, o0[reg + 1] * invl);
      *(uint32_t*)(orow + hd + 32) = cvtpk_bf16(o1[reg] * invl, o1[reg + 1] * invl);
    }
  }
}

extern "C" void kernel_launch(void* const* d_in, const int* in_sizes, int n_in,
                              void* d_out, int out_size, void* d_ws, size_t ws_size,
                              hipStream_t stream) {
  const float* x = (const float*)d_in[0];
  const float* kv = (const float*)d_in[1];
  const float* Wq = (const float*)d_in[2];
  const float* bq = (const float*)d_in[3];
  const float* Wk = (const float*)d_in[4];
  const float* bk = (const float*)d_in[5];
  const float* Wv = (const float*)d_in[6];
  const float* bv = (const float*)d_in[7];
  const float* Wo = (const float*)d_in[8];
  const float* bo = (const float*)d_in[9];
  float* out = (float*)d_out;

  char* ws = (char*)d_ws;
  uint16_t* xb = (uint16_t*)ws;   ws += (size_t)CB * CS * CD * 2;
  uint16_t* kvb = (uint16_t*)ws;  ws += (size_t)CB * CS * CD * 2;
  uint16_t* WqT = (uint16_t*)ws;  ws += (size_t)CD * CD * 2;        // rows 0..2047
  uint16_t* WkT = (uint16_t*)ws;  ws += (size_t)(CG * CHD) * CD * 2;  // 2048..2559
  uint16_t* WvT = (uint16_t*)ws;  ws += (size_t)(CG * CHD) * CD * 2;  // 2560..3071
  uint16_t* WoT = (uint16_t*)ws;  ws += (size_t)CD * CD * 2;        // 3072..5119
  uint16_t* Qb = (uint16_t*)ws;   ws += (size_t)CB * CH * CS * CHD * 2;
  uint16_t* Kb = (uint16_t*)ws;   ws += (size_t)CB * CG * CS * CHD * 2;
  uint16_t* VTb = (uint16_t*)ws;  ws += (size_t)CB * CG * CHD * CS * 2;
  uint16_t* attnb = (uint16_t*)ws;
  (void)WkT; (void)WvT;

  const int NTOK = CB * CS;  // 4096
  const int nel = CB * CS * CD;

  cast_both_kernel<<<2 * nel / 4 / 256, 256, 0, stream>>>(x, kv, xb, kvb, nel);
  transpose_all_kernel<<<dim3(5120 / 32, CD / 32), 256, 0, stream>>>(
      Wq, Wk, Wv, Wo, WqT);

  gemm_qkv_kernel<<<dim3(3072 / 128, NTOK / 128), 512, 0, stream>>>(
      xb, kvb, WqT, bq, bk, bv, Qb, Kb, VTb);

  flash_attn_kernel<<<dim3(CS / 256, CH, CB), 256, 0, stream>>>(Qb, Kb, VTb, attnb);

  gemm_out_kernel<<<dim3(CD / 128, NTOK / 128), 512, 0, stream>>>(
      attnb, WoT, bo, out, NTOK, CD, CD);
}

// Round 13
// 195.576 us; speedup vs baseline: 1.2983x; 1.0226x over previous
//
#include <hip/hip_runtime.h>
#include <hip/hip_bf16.h>
#include <stdint.h>

namespace {
constexpr int CB = 2, CS = 2048, CD = 2048, CH = 32, CG = 8, CHD = 64, CGS = 4;

typedef __bf16 bf16x8 __attribute__((ext_vector_type(8)));
typedef float f32x4 __attribute__((ext_vector_type(4)));
typedef float f32x16 __attribute__((ext_vector_type(16)));
typedef uint32_t u32x4 __attribute__((ext_vector_type(4)));
typedef uint16_t u16x8 __attribute__((ext_vector_type(8)));

__device__ inline uint16_t f2bf(float f) {
  uint32_t u = __float_as_uint(f);
  u += 0x7fffu + ((u >> 16) & 1u);
  return (uint16_t)(u >> 16);
}

__device__ inline void gload_lds16(const void* g, void* l) {
  __builtin_amdgcn_global_load_lds(
      (const __attribute__((address_space(1))) void*)g,
      (__attribute__((address_space(3))) void*)l, 16, 0, 0);
}

__device__ inline uint32_t cvtpk_bf16(float lo, float hi) {
  uint32_t r;
  asm("v_cvt_pk_bf16_f32 %0, %1, %2" : "=v"(r) : "v"(lo), "v"(hi));
  return r;
}
// in-place: a <- {a.lo, b.lo}, b <- {a.hi, b.hi}
__device__ inline void pl32swap(uint32_t& a, uint32_t& b) {
  asm("v_permlane32_swap_b32 %0, %1" : "+v"(a), "+v"(b));
}
}  // namespace

// ------------- fused cast f32 -> bf16 for x and kv -------------
__global__ __launch_bounds__(256) void cast_both_kernel(
    const float* __restrict__ x, const float* __restrict__ kv,
    uint16_t* __restrict__ xb, uint16_t* __restrict__ kvb, int nel) {
  int i = (blockIdx.x * 256 + threadIdx.x) * 4;
  const float* in;
  uint16_t* out;
  if (i < nel) { in = x + i; out = xb + i; }
  else         { in = kv + (i - nel); out = kvb + (i - nel); }
  const float4 v = *(const float4*)in;
  ushort4 o;
  o.x = f2bf(v.x); o.y = f2bf(v.y); o.z = f2bf(v.z); o.w = f2bf(v.w);
  *(ushort4*)out = o;
}

// ------------- transpose+cast all 4 weights into FRAGMENT-PACKED layout --
// Packed rows 0..2047: WqT, 2048..2559: WkT, 2560..3071: WvT, 3072..5119: WoT
// Layout: P[nb][kb][lane][j], nb=n>>4, kb=k>>5, lane=((k>>3)&3)*16+(n&15),
// j=k&7. A wave's B-fragment (16 rows x 32 K) = 1 KB contiguous, lane-major.
__global__ __launch_bounds__(256) void transpose_all_kernel(
    const float* __restrict__ Wq, const float* __restrict__ Wk,
    const float* __restrict__ Wv, const float* __restrict__ Wo,
    uint16_t* __restrict__ out) {
  __shared__ uint16_t tile[32][33];
  const int gn0 = blockIdx.x * 32;  // packed row block (0..5119)
  const int k0 = blockIdx.y * 32;
  const float* in;
  int Nr, start;
  if (gn0 < 2048)      { in = Wq; Nr = 2048; start = 0; }
  else if (gn0 < 2560) { in = Wk; Nr = 512;  start = 2048; }
  else if (gn0 < 3072) { in = Wv; Nr = 512;  start = 2560; }
  else                 { in = Wo; Nr = 2048; start = 3072; }
  const int n0 = gn0 - start;
  const int tx = threadIdx.x & 31, tg = threadIdx.x >> 5;
#pragma unroll
  for (int rr = 0; rr < 4; ++rr) {
    int k = tg * 4 + rr;
    tile[k][tx] = f2bf(in[(size_t)(k0 + k) * Nr + n0 + tx]);  // tile[k][n]=W^T[n][k]
  }
  __syncthreads();
  if (threadIdx.x < 128) {
    int n = threadIdx.x >> 2, k8 = threadIdx.x & 3;  // 32 n x 4 k-octets
    u16x8 v;
#pragma unroll
    for (int j = 0; j < 8; ++j) v[j] = tile[k8 * 8 + j][n];
    int n_abs = gn0 + n;
    size_t flat = (((size_t)(n_abs >> 4) * 64 + (size_t)(k0 >> 5)) * 64 +
                   (size_t)(k8 * 16 + (n_abs & 15))) * 8;
    *(u16x8*)(out + flat) = v;
  }
}

// ------------- fused QKV projection GEMM (A-only LDS, B global->reg) -----
// 128x128 tile, BK=32, 256 thr / 4 waves (2M x 2N, 64x64/wave).
// A: triple-buffered LDS (24 KiB), gload_lds, verified 4-slot swizzle.
// B: fragment-packed global loads direct to regs, depth-2 double-buffer.
// Counted vmcnt(6) = loadB(t+1)[4] + stageA(t+1)[2] younger; never 0 mid-loop.
// LDS traffic 0.023 B/FLOP (was 0.046-0.061) -> LDS no longer caps MFMA.
__global__ __launch_bounds__(256, 2) void gemm_qkv_kernel(
    const uint16_t* __restrict__ xb, const uint16_t* __restrict__ kvb,
    const uint16_t* __restrict__ WTp,
    const float* __restrict__ bq, const float* __restrict__ bk,
    const float* __restrict__ bv,
    uint16_t* __restrict__ Qb, uint16_t* __restrict__ Kb,
    uint16_t* __restrict__ VTb) {
  constexpr int BM = 128, BK = 32, K = 2048, NT = K / BK;  // 64
  constexpr int ASZ = BM * BK;  // 4096 elems = 8 KB
  __shared__ uint16_t Asm[3 * ASZ];  // 24 KB
  const int tid = threadIdx.x;
  const int w = tid >> 6, l = tid & 63;
  const int wr = w >> 1, wc = w & 1;   // 2M x 2N waves; per-wave 64x64
  const int l15 = l & 15, lq = l >> 4;

  // XCD-aware bijective swizzle (nwg = 768): each XCD owns 3 n-columns ->
  // its B slice = 3*128*2048*2B = 1.5 MB, fits per-XCD L2.
  const int gx = gridDim.x;  // 24
  int bid = blockIdx.y * gx + blockIdx.x;
  const int nwg = gx * gridDim.y;
  bid = (bid & 7) * (nwg >> 3) + (bid >> 3);
  const int m0 = (bid / gx) * BM, n0 = (bid % gx) * 128;
  const uint16_t* A = (n0 < 2048) ? xb : kvb;
  const int nbb = (n0 >> 4) + wc * 4;

  auto stageA = [&](int buf, int t) {
    uint16_t* base = Asm + buf * ASZ;
    const int k0 = t * BK;
#pragma unroll
    for (int i = 0; i < 2; ++i) {
      int g = i * 256 + tid;            // 512 granules (128 rows x 4)
      int row = g >> 2, slot = g & 3;
      int kq = slot ^ ((row >> 1) & 3);
      gload_lds16(A + (size_t)(m0 + row) * K + k0 + kq * 8, base + g * 8);
    }
  };
  auto loadB = [&](bf16x8* dst, int t) {
#pragma unroll
    for (int n = 0; n < 4; ++n)
      dst[n] = *(const bf16x8*)(
          WTp + ((((size_t)(nbb + n)) * 64 + (size_t)t) << 9) + (size_t)l * 8);
  };

  int aOff[4];
#pragma unroll
  for (int m = 0; m < 4; ++m) {
    int row = wr * 64 + m * 16 + l15;
    aOff[m] = (row * BK + (lq ^ ((row >> 1) & 3)) * 8) * 2;
  }

  f32x4 acc[4][4] = {};
  bf16x8 bE[4], bO[4];

  loadB(bE, 0); stageA(0, 0);
  loadB(bO, 1); stageA(1, 1);

  int bt = 0, bs = 2;

#define QKV_SUB(T, BREG, VM)                                                 \
  {                                                                          \
    asm volatile("s_waitcnt vmcnt(" #VM ")" ::: "memory");                   \
    __builtin_amdgcn_s_barrier();                                            \
    asm volatile("" ::: "memory");                                           \
    const char* buf_ = (const char*)(Asm + bt * ASZ);                        \
    bf16x8 af[4];                                                            \
    _Pragma("unroll") for (int m = 0; m < 4; ++m)                            \
        af[m] = *(const bf16x8*)(buf_ + aOff[m]);                            \
    __builtin_amdgcn_s_setprio(1);                                           \
    _Pragma("unroll") for (int m = 0; m < 4; ++m)                            \
        _Pragma("unroll") for (int n = 0; n < 4; ++n)                        \
            acc[m][n] = __builtin_amdgcn_mfma_f32_16x16x32_bf16(             \
                af[m], BREG[n], acc[m][n], 0, 0, 0);                         \
    __builtin_amdgcn_s_setprio(0);                                           \
    if ((T) + 2 < NT) { loadB(BREG, (T) + 2); stageA(bs, (T) + 2); }         \
    bt = bt == 2 ? 0 : bt + 1;                                               \
    bs = bs == 2 ? 0 : bs + 1;                                               \
  }

  for (int t = 0; t < NT - 2; t += 2) {
    QKV_SUB(t, bE, 6);
    QKV_SUB(t + 1, bO, 6);
  }
  QKV_SUB(NT - 2, bE, 6);
  QKV_SUB(NT - 1, bO, 0);
#undef QKV_SUB

#pragma unroll
  for (int m = 0; m < 4; ++m)
#pragma unroll
    for (int n = 0; n < 4; ++n)
#pragma unroll
      for (int r = 0; r < 4; ++r) {
        int gm = m0 + wr * 64 + m * 16 + lq * 4 + r;
        int gn = n0 + wc * 64 + n * 16 + l15;
        int b = gm >> 11, s = gm & (CS - 1);
        if (n0 < 2048) {  // Q (pre-scaled)
          float v = (acc[m][n][r] + bq[gn]) * (0.125f * 1.44269504088896340736f);
          int h = gn >> 6, hd = gn & 63;
          Qb[(((size_t)(b * CH + h)) * CS + s) * CHD + hd] = f2bf(v);
        } else if (n0 < 2560) {  // K
          int gn2 = gn - 2048;
          float v = acc[m][n][r] + bk[gn2];
          int gh = gn2 >> 6, hd = gn2 & 63;
          Kb[(((size_t)(b * CG + gh)) * CS + s) * CHD + hd] = f2bf(v);
        } else {  // V -> VT[B,G,HD,S]
          int gn2 = gn - 2560;
          float v = acc[m][n][r] + bv[gn2];
          int gh = gn2 >> 6, hd = gn2 & 63;
          VTb[(((size_t)(b * CG + gh)) * CHD + hd) * CS + s] = f2bf(v);
        }
      }
}

// ------------- output projection GEMM (A-only LDS, B global->reg) --------
__global__ __launch_bounds__(256, 2) void gemm_out_kernel(
    const uint16_t* __restrict__ A, const uint16_t* __restrict__ Btp,
    const float* __restrict__ bias, float* __restrict__ Cout,
    int M, int N, int Kdim) {
  constexpr int BM = 128, BK = 32, K = 2048, NT = K / BK;  // 64
  constexpr int ASZ = BM * BK;
  __shared__ uint16_t Asm[3 * ASZ];  // 24 KB
  const int tid = threadIdx.x;
  const int w = tid >> 6, l = tid & 63;
  const int wr = w >> 1, wc = w & 1;
  const int l15 = l & 15, lq = l >> 4;

  const int gx = gridDim.x;  // 16
  int bid = blockIdx.y * gx + blockIdx.x;
  const int nwg = gx * gridDim.y;
  bid = (bid & 7) * (nwg >> 3) + (bid >> 3);
  const int m0 = (bid / gx) * BM, n0 = (bid % gx) * 128;
  const int nbb = (n0 >> 4) + wc * 4;

  auto stageA = [&](int buf, int t) {
    uint16_t* base = Asm + buf * ASZ;
    const int k0 = t * BK;
#pragma unroll
    for (int i = 0; i < 2; ++i) {
      int g = i * 256 + tid;
      int row = g >> 2, slot = g & 3;
      int kq = slot ^ ((row >> 1) & 3);
      gload_lds16(A + (size_t)(m0 + row) * K + k0 + kq * 8, base + g * 8);
    }
  };
  auto loadB = [&](bf16x8* dst, int t) {
#pragma unroll
    for (int n = 0; n < 4; ++n)
      dst[n] = *(const bf16x8*)(
          Btp + ((((size_t)(nbb + n)) * 64 + (size_t)t) << 9) + (size_t)l * 8);
  };

  int aOff[4];
#pragma unroll
  for (int m = 0; m < 4; ++m) {
    int row = wr * 64 + m * 16 + l15;
    aOff[m] = (row * BK + (lq ^ ((row >> 1) & 3)) * 8) * 2;
  }

  f32x4 acc[4][4] = {};
  bf16x8 bE[4], bO[4];

  loadB(bE, 0); stageA(0, 0);
  loadB(bO, 1); stageA(1, 1);

  int bt = 0, bs = 2;

#define OUT_SUB(T, BREG, VM)                                                 \
  {                                                                          \
    asm volatile("s_waitcnt vmcnt(" #VM ")" ::: "memory");                   \
    __builtin_amdgcn_s_barrier();                                            \
    asm volatile("" ::: "memory");                                           \
    const char* buf_ = (const char*)(Asm + bt * ASZ);                        \
    bf16x8 af[4];                                                            \
    _Pragma("unroll") for (int m = 0; m < 4; ++m)                            \
        af[m] = *(const bf16x8*)(buf_ + aOff[m]);                            \
    __builtin_amdgcn_s_setprio(1);                                           \
    _Pragma("unroll") for (int m = 0; m < 4; ++m)                            \
        _Pragma("unroll") for (int n = 0; n < 4; ++n)                        \
            acc[m][n] = __builtin_amdgcn_mfma_f32_16x16x32_bf16(             \
                af[m], BREG[n], acc[m][n], 0, 0, 0);                         \
    __builtin_amdgcn_s_setprio(0);                                           \
    if ((T) + 2 < NT) { loadB(BREG, (T) + 2); stageA(bs, (T) + 2); }         \
    bt = bt == 2 ? 0 : bt + 1;                                               \
    bs = bs == 2 ? 0 : bs + 1;                                               \
  }

  for (int t = 0; t < NT - 2; t += 2) {
    OUT_SUB(t, bE, 6);
    OUT_SUB(t + 1, bO, 6);
  }
  OUT_SUB(NT - 2, bE, 6);
  OUT_SUB(NT - 1, bO, 0);
#undef OUT_SUB

#pragma unroll
  for (int m = 0; m < 4; ++m)
#pragma unroll
    for (int n = 0; n < 4; ++n)
#pragma unroll
      for (int r = 0; r < 4; ++r) {
        int gm = m0 + wr * 64 + m * 16 + lq * 4 + r;
        int gn = n0 + wc * 64 + n * 16 + l15;
        Cout[(size_t)gm * N + gn] = acc[m][n][r] + bias[gn];
      }
}

// ---------------- causal flash attention, balanced pairs, KVBLK=128 ------
// (unchanged from passing R11/R12 version)
__global__ __launch_bounds__(256, 2) void flash_attn_kernel(
    const uint16_t* __restrict__ Q, const uint16_t* __restrict__ K,
    const uint16_t* __restrict__ VT, uint16_t* __restrict__ Aout) {
  constexpr int NQB = CS / 128;  // 16
  constexpr int KV = 128;        // keys per tile
  __shared__ __align__(16) uint16_t Ksm[2][KV * CHD];  // [key][hd] 16KB each
  __shared__ __align__(16) uint16_t Vsm[2][CHD * KV];  // [hd][key] 16KB each
  const int tid = threadIdx.x, w = tid >> 6, l = tid & 63;
  const int l31 = l & 31, hi = l >> 5;
  const int x = blockIdx.x;  // 0..NQB/2-1
  const int h = blockIdx.y, b = blockIdx.z, g = h >> 2;

  const uint16_t* Qbase = Q + ((size_t)(b * CH + h)) * CS * CHD;
  const uint16_t* Kbase = K + ((size_t)(b * CG + g)) * CS * CHD;
  const uint16_t* Vbase = VT + ((size_t)(b * CG + g)) * CHD * CS;

  auto stage = [&](int buf, int kt) {
#pragma unroll
    for (int i = 0; i < 4; ++i) {
      int gK = i * 256 + tid;           // 1024 granules, row=key, 8/row
      int rowK = gK >> 3, slotK = gK & 7;
      int kqK = slotK ^ (rowK & 7);
      gload_lds16(Kbase + ((size_t)kt * KV + rowK) * CHD + kqK * 8,
                  &Ksm[buf][gK * 8]);
    }
#pragma unroll
    for (int i = 0; i < 4; ++i) {
      int gV = i * 256 + tid;           // 1024 granules, row=hd, 16/row
      int rowV = gV >> 4, slotV = gV & 15;
      int kqV = slotV ^ (rowV & 15);
      gload_lds16(Vbase + (size_t)rowV * CS + kt * KV + kqV * 8,
                  &Vsm[buf][gV * 8]);
    }
  };

  int kOff[4][4];
#pragma unroll
  for (int c = 0; c < 4; ++c)
#pragma unroll
    for (int kc = 0; kc < 4; ++kc) {
      int row = c * 32 + l31;
      kOff[c][kc] = ((row * CHD + kc * 16 + hi * 8) * 2) ^ ((row & 7) << 4);
    }
  int vOff[2][8];
#pragma unroll
  for (int c = 0; c < 2; ++c)
#pragma unroll
    for (int ks = 0; ks < 8; ++ks) {
      int row = c * 32 + l31;
      vOff[c][ks] = ((row * KV + ks * 16 + hi * 8) * 2) ^ ((row & 15) << 4);
    }

#pragma unroll 1
  for (int job = 0; job < 2; ++job) {
    const int qb = job == 0 ? (NQB - 1 - x) : x;
    const int qrow = qb * 128 + w * 32 + l31;
    const int wbase = qb * 128 + w * 32;  // wave's FIRST q-row

    bf16x8 qf[4];
#pragma unroll
    for (int kc = 0; kc < 4; ++kc)
      qf[kc] = *(const bf16x8*)(Qbase + (size_t)qrow * CHD + kc * 16 + hi * 8);

    f32x16 o0 = {}, o1 = {};
    float mrun = -3e38f, lrun = 0.f;
    const int nt = qb + 1;

    stage(0, 0);
    asm volatile("s_waitcnt vmcnt(0)" ::: "memory");
    __syncthreads();

    for (int kt = 0; kt < nt; ++kt) {
      const int cur = kt & 1;
      if (kt + 1 < nt) stage(cur ^ 1, kt + 1);

      const char* ksmb = (const char*)Ksm[cur];
      const char* vsmb = (const char*)Vsm[cur];

      f32x16 p0 = {}, p1 = {}, p2 = {}, p3 = {};
      __builtin_amdgcn_s_setprio(1);
#pragma unroll
      for (int kc = 0; kc < 4; ++kc) {
        bf16x8 ka0 = *(const bf16x8*)(ksmb + kOff[0][kc]);
        bf16x8 ka1 = *(const bf16x8*)(ksmb + kOff[1][kc]);
        bf16x8 ka2 = *(const bf16x8*)(ksmb + kOff[2][kc]);
        bf16x8 ka3 = *(const bf16x8*)(ksmb + kOff[3][kc]);
        p0 = __builtin_amdgcn_mfma_f32_32x32x16_bf16(ka0, qf[kc], p0, 0, 0, 0);
        p1 = __builtin_amdgcn_mfma_f32_32x32x16_bf16(ka1, qf[kc], p1, 0, 0, 0);
        p2 = __builtin_amdgcn_mfma_f32_32x32x16_bf16(ka2, qf[kc], p2, 0, 0, 0);
        p3 = __builtin_amdgcn_mfma_f32_32x32x16_bf16(ka3, qf[kc], p3, 0, 0, 0);
      }
      __builtin_amdgcn_s_setprio(0);

      const bool need_mask = (kt * KV + KV - 1 > wbase);
      if (need_mask) {
#pragma unroll
        for (int r = 0; r < 16; ++r) {
          int keyb = kt * KV + (r & 3) + 8 * (r >> 2) + 4 * hi;
          if (keyb > qrow) p0[r] = -3e38f;
          if (keyb + 32 > qrow) p1[r] = -3e38f;
          if (keyb + 64 > qrow) p2[r] = -3e38f;
          if (keyb + 96 > qrow) p3[r] = -3e38f;
        }
      }
      float pmax = -3e38f;
#pragma unroll
      for (int r = 0; r < 16; ++r) {
        pmax = fmaxf(pmax, fmaxf(fmaxf(p0[r], p1[r]), fmaxf(p2[r], p3[r])));
      }
      pmax = fmaxf(pmax, __shfl_xor(pmax, 32));

      if (!__all(pmax <= mrun + 8.f)) {
        float mnew = fmaxf(mrun, pmax);
        float alpha = __builtin_amdgcn_exp2f(mrun - mnew);
#pragma unroll
        for (int r = 0; r < 16; ++r) { o0[r] *= alpha; o1[r] *= alpha; }
        lrun *= alpha;
        mrun = mnew;
      }
      float s = 0.f;
#pragma unroll
      for (int r = 0; r < 16; ++r) {
        float e0 = __builtin_amdgcn_exp2f(p0[r] - mrun);
        float e1 = __builtin_amdgcn_exp2f(p1[r] - mrun);
        float e2 = __builtin_amdgcn_exp2f(p2[r] - mrun);
        float e3 = __builtin_amdgcn_exp2f(p3[r] - mrun);
        p0[r] = e0; p1[r] = e1; p2[r] = e2; p3[r] = e3;
        s += (e0 + e1) + (e2 + e3);
      }
      s += __shfl_xor(s, 32);
      lrun += s;

      u32x4 paw[8];
#pragma unroll
      for (int k = 0; k < 8; ++k) {
        const int base = (k & 1) * 8;
        const int c = k >> 1;
        const f32x16& pc = (c == 0) ? p0 : (c == 1) ? p1 : (c == 2) ? p2 : p3;
        uint32_t c01 = cvtpk_bf16(pc[base + 0], pc[base + 1]);
        uint32_t c23 = cvtpk_bf16(pc[base + 2], pc[base + 3]);
        uint32_t c45 = cvtpk_bf16(pc[base + 4], pc[base + 5]);
        uint32_t c67 = cvtpk_bf16(pc[base + 6], pc[base + 7]);
        pl32swap(c01, c45);
        pl32swap(c23, c67);
        paw[k] = (u32x4){c01, c23, c45, c67};
      }

      __builtin_amdgcn_s_setprio(1);
#pragma unroll
      for (int ks = 0; ks < 8; ++ks) {
        bf16x8 vb0 = *(const bf16x8*)(vsmb + vOff[0][ks]);
        bf16x8 vb1 = *(const bf16x8*)(vsmb + vOff[1][ks]);
        bf16x8 pb = __builtin_bit_cast(bf16x8, paw[ks]);
        o0 = __builtin_amdgcn_mfma_f32_32x32x16_bf16(vb0, pb, o0, 0, 0, 0);
        o1 = __builtin_amdgcn_mfma_f32_32x32x16_bf16(vb1, pb, o1, 0, 0, 0);
      }
      __builtin_amdgcn_s_setprio(0);

      asm volatile("s_waitcnt vmcnt(0)" ::: "memory");
      __syncthreads();
    }

    float invl = 1.f / lrun;
    uint16_t* orow = Aout + ((size_t)b * CS + qrow) * CD + (size_t)h * CHD;
#pragma unroll
    for (int k = 0; k < 8; ++k) {
      int reg = 2 * k;
      int hd = (reg & 3) + 8 * (reg >> 2) + 4 * hi;
      *(uint32_t*)(orow + hd) = cvtpk_bf16(o0[reg] * invl, o0[reg + 1] * invl);
      *(uint32_t*)(orow + hd + 32) = cvtpk_bf16(o1[reg] * invl, o1[reg + 1] * invl);
    }
  }
}

extern "C" void kernel_launch(void* const* d_in, const int* in_sizes, int n_in,
                              void* d_out, int out_size, void* d_ws, size_t ws_size,
                              hipStream_t stream) {
  const float* x = (const float*)d_in[0];
  const float* kv = (const float*)d_in[1];
  const float* Wq = (const float*)d_in[2];
  const float* bq = (const float*)d_in[3];
  const float* Wk = (const float*)d_in[4];
  const float* bk = (const float*)d_in[5];
  const float* Wv = (const float*)d_in[6];
  const float* bv = (const float*)d_in[7];
  const float* Wo = (const float*)d_in[8];
  const float* bo = (const float*)d_in[9];
  float* out = (float*)d_out;

  char* ws = (char*)d_ws;
  uint16_t* xb = (uint16_t*)ws;   ws += (size_t)CB * CS * CD * 2;
  uint16_t* kvb = (uint16_t*)ws;  ws += (size_t)CB * CS * CD * 2;
  uint16_t* WqT = (uint16_t*)ws;  ws += (size_t)CD * CD * 2;        // packed rows 0..2047
  uint16_t* WkT = (uint16_t*)ws;  ws += (size_t)(CG * CHD) * CD * 2;  // 2048..2559
  uint16_t* WvT = (uint16_t*)ws;  ws += (size_t)(CG * CHD) * CD * 2;  // 2560..3071
  uint16_t* WoT = (uint16_t*)ws;  ws += (size_t)CD * CD * 2;        // 3072..5119
  uint16_t* Qb = (uint16_t*)ws;   ws += (size_t)CB * CH * CS * CHD * 2;
  uint16_t* Kb = (uint16_t*)ws;   ws += (size_t)CB * CG * CS * CHD * 2;
  uint16_t* VTb = (uint16_t*)ws;  ws += (size_t)CB * CG * CHD * CS * 2;
  uint16_t* attnb = (uint16_t*)ws;
  (void)WkT; (void)WvT;

  const int NTOK = CB * CS;  // 4096
  const int nel = CB * CS * CD;

  cast_both_kernel<<<2 * nel / 4 / 256, 256, 0, stream>>>(x, kv, xb, kvb, nel);
  transpose_all_kernel<<<dim3(5120 / 32, CD / 32), 256, 0, stream>>>(
      Wq, Wk, Wv, Wo, WqT);

  gemm_qkv_kernel<<<dim3(3072 / 128, NTOK / 128), 256, 0, stream>>>(
      xb, kvb, WqT, bq, bk, bv, Qb, Kb, VTb);

  flash_attn_kernel<<<dim3(CS / 256, CH, CB), 256, 0, stream>>>(Qb, Kb, VTb, attnb);

  gemm_out_kernel<<<dim3(CD / 128, NTOK / 128), 256, 0, stream>>>(
      attnb, WoT, bo, out, NTOK, CD, CD);
}

// Round 14
// 186.309 us; speedup vs baseline: 1.3628x; 1.0497x over previous
//
#include <hip/hip_runtime.h>
#include <hip/hip_bf16.h>
#include <stdint.h>

namespace {
constexpr int CB = 2, CS = 2048, CD = 2048, CH = 32, CG = 8, CHD = 64, CGS = 4;

typedef __bf16 bf16x8 __attribute__((ext_vector_type(8)));
typedef float f32x4 __attribute__((ext_vector_type(4)));
typedef float f32x16 __attribute__((ext_vector_type(16)));
typedef uint32_t u32x4 __attribute__((ext_vector_type(4)));
typedef uint16_t u16x8 __attribute__((ext_vector_type(8)));

__device__ inline uint16_t f2bf(float f) {
  uint32_t u = __float_as_uint(f);
  u += 0x7fffu + ((u >> 16) & 1u);
  return (uint16_t)(u >> 16);
}

__device__ inline void gload_lds16(const void* g, void* l) {
  __builtin_amdgcn_global_load_lds(
      (const __attribute__((address_space(1))) void*)g,
      (__attribute__((address_space(3))) void*)l, 16, 0, 0);
}

__device__ inline uint32_t cvtpk_bf16(float lo, float hi) {
  uint32_t r;
  asm("v_cvt_pk_bf16_f32 %0, %1, %2" : "=v"(r) : "v"(lo), "v"(hi));
  return r;
}
// in-place: a <- {a.lo, b.lo}, b <- {a.hi, b.hi}
__device__ inline void pl32swap(uint32_t& a, uint32_t& b) {
  asm("v_permlane32_swap_b32 %0, %1" : "+v"(a), "+v"(b));
}
}  // namespace

// ------------- fused cast f32 -> bf16 for x and kv -------------
__global__ __launch_bounds__(256) void cast_both_kernel(
    const float* __restrict__ x, const float* __restrict__ kv,
    uint16_t* __restrict__ xb, uint16_t* __restrict__ kvb, int nel) {
  int i = (blockIdx.x * 256 + threadIdx.x) * 4;
  const float* in;
  uint16_t* out;
  if (i < nel) { in = x + i; out = xb + i; }
  else         { in = kv + (i - nel); out = kvb + (i - nel); }
  const float4 v = *(const float4*)in;
  ushort4 o;
  o.x = f2bf(v.x); o.y = f2bf(v.y); o.z = f2bf(v.z); o.w = f2bf(v.w);
  *(ushort4*)out = o;
}

// ------------- transpose+cast all 4 weights into FRAGMENT-PACKED layout --
// Packed rows 0..2047: WqT, 2048..2559: WkT, 2560..3071: WvT, 3072..5119: WoT
// Layout: P[nb][kb][lane][j], nb=n>>4, kb=k>>5, lane=((k>>3)&3)*16+(n&15),
// j=k&7. A wave's B-fragment (16 rows x 32 K) = 1 KB contiguous, lane-major.
__global__ __launch_bounds__(256) void transpose_all_kernel(
    const float* __restrict__ Wq, const float* __restrict__ Wk,
    const float* __restrict__ Wv, const float* __restrict__ Wo,
    uint16_t* __restrict__ out) {
  __shared__ uint16_t tile[32][33];
  const int gn0 = blockIdx.x * 32;  // packed row block (0..5119)
  const int k0 = blockIdx.y * 32;
  const float* in;
  int Nr, start;
  if (gn0 < 2048)      { in = Wq; Nr = 2048; start = 0; }
  else if (gn0 < 2560) { in = Wk; Nr = 512;  start = 2048; }
  else if (gn0 < 3072) { in = Wv; Nr = 512;  start = 2560; }
  else                 { in = Wo; Nr = 2048; start = 3072; }
  const int n0 = gn0 - start;
  const int tx = threadIdx.x & 31, tg = threadIdx.x >> 5;
#pragma unroll
  for (int rr = 0; rr < 4; ++rr) {
    int k = tg * 4 + rr;
    tile[k][tx] = f2bf(in[(size_t)(k0 + k) * Nr + n0 + tx]);  // tile[k][n]=W^T[n][k]
  }
  __syncthreads();
  if (threadIdx.x < 128) {
    int n = threadIdx.x >> 2, k8 = threadIdx.x & 3;  // 32 n x 4 k-octets
    u16x8 v;
#pragma unroll
    for (int j = 0; j < 8; ++j) v[j] = tile[k8 * 8 + j][n];
    int n_abs = gn0 + n;
    size_t flat = (((size_t)(n_abs >> 4) * 64 + (size_t)(k0 >> 5)) * 64 +
                   (size_t)(k8 * 16 + (n_abs & 15))) * 8;
    *(u16x8*)(out + flat) = v;
  }
}

// ------------- fused QKV projection GEMM (BK=64, A-only LDS, B->reg) -----
// 128x128 tile, BK=64 (32 steps: half the barriers of BK=32), 4 waves.
// A: triple-buffered LDS (48 KiB, 3 blocks/CU), slot^(row&7) swizzle
// (verified 0-conflict). B: fragment-packed global->reg, single reg set
// (loaded after MFMA cluster, WAR-ordered). Uniform vmcnt(4) at step top:
// queue = {A(t):4, B(t):8, A(t+1):4} -> retires A(t)+B(t), never 0 mid-loop.
__global__ __launch_bounds__(256, 3) void gemm_qkv_kernel(
    const uint16_t* __restrict__ xb, const uint16_t* __restrict__ kvb,
    const uint16_t* __restrict__ WTp,
    const float* __restrict__ bq, const float* __restrict__ bk,
    const float* __restrict__ bv,
    uint16_t* __restrict__ Qb, uint16_t* __restrict__ Kb,
    uint16_t* __restrict__ VTb) {
  constexpr int BM = 128, BK = 64, K = 2048, NT = K / BK;  // 32
  constexpr int ASZ = BM * BK;  // 8192 elems = 16 KB
  __shared__ uint16_t Asm[3 * ASZ];  // 48 KB
  const int tid = threadIdx.x;
  const int w = tid >> 6, l = tid & 63;
  const int wr = w >> 1, wc = w & 1;   // 2M x 2N waves; per-wave 64x64
  const int l15 = l & 15, lq = l >> 4;

  // XCD-aware bijective swizzle (nwg = 768)
  const int gx = gridDim.x;  // 24
  int bid = blockIdx.y * gx + blockIdx.x;
  const int nwg = gx * gridDim.y;
  bid = (bid & 7) * (nwg >> 3) + (bid >> 3);
  const int m0 = (bid / gx) * BM, n0 = (bid % gx) * 128;
  const uint16_t* A = (n0 < 2048) ? xb : kvb;
  const int nbb = (n0 >> 4) + wc * 4;

  auto stageA = [&](int buf, int t) {
    uint16_t* base = Asm + buf * ASZ;
    const int k0 = t * BK;
#pragma unroll
    for (int i = 0; i < 4; ++i) {
      int g = i * 256 + tid;            // 1024 granules (128 rows x 8)
      int row = g >> 3, slot = g & 7;
      int kq = slot ^ (row & 7);
      gload_lds16(A + (size_t)(m0 + row) * K + k0 + kq * 8, base + g * 8);
    }
  };
  // packed B: kb = 2t+kk (32-K units)
  auto loadB = [&](bf16x8 (*dst)[4], int t) {
#pragma unroll
    for (int kk = 0; kk < 2; ++kk)
#pragma unroll
      for (int n = 0; n < 4; ++n)
        dst[kk][n] = *(const bf16x8*)(
            WTp + ((((size_t)(nbb + n)) * 64 + (size_t)(2 * t + kk)) << 9) +
            (size_t)l * 8);
  };

  int aOff[2][4];
#pragma unroll
  for (int kk = 0; kk < 2; ++kk)
#pragma unroll
    for (int m = 0; m < 4; ++m) {
      int row = wr * 64 + m * 16 + l15;
      aOff[kk][m] = (row * BK + ((kk * 4 + lq) ^ (row & 7)) * 8) * 2;
    }

  f32x4 acc[4][4] = {};
  bf16x8 brg[2][4];

  loadB(brg, 0);      // 8 loads (oldest)
  stageA(0, 0);       // 4
  stageA(1, 1);       // 4

  int bt = 0, bs = 2;
  for (int t = 0; t < NT; ++t) {
    // retire A(t) and B(t); A(t+1) (newest 4) may stay in flight
    if (t < NT - 1) asm volatile("s_waitcnt vmcnt(4)" ::: "memory");
    else            asm volatile("s_waitcnt vmcnt(0)" ::: "memory");
    __builtin_amdgcn_s_barrier();
    asm volatile("" ::: "memory");

    const char* buf = (const char*)(Asm + bt * ASZ);
    bf16x8 af[2][4];
#pragma unroll
    for (int kk = 0; kk < 2; ++kk)
#pragma unroll
      for (int m = 0; m < 4; ++m)
        af[kk][m] = *(const bf16x8*)(buf + aOff[kk][m]);

    __builtin_amdgcn_s_setprio(1);
#pragma unroll
    for (int kk = 0; kk < 2; ++kk)
#pragma unroll
      for (int m = 0; m < 4; ++m)
#pragma unroll
        for (int n = 0; n < 4; ++n)
          acc[m][n] = __builtin_amdgcn_mfma_f32_16x16x32_bf16(
              af[kk][m], brg[kk][n], acc[m][n], 0, 0, 0);
    __builtin_amdgcn_s_setprio(0);

    if (t + 1 < NT) loadB(brg, t + 1);   // 8 loads (WAR after MFMA)
    if (t + 2 < NT) stageA(bs, t + 2);   // 4 loads (newest)

    bt = bt == 2 ? 0 : bt + 1;
    bs = bs == 2 ? 0 : bs + 1;
  }

#pragma unroll
  for (int m = 0; m < 4; ++m)
#pragma unroll
    for (int n = 0; n < 4; ++n)
#pragma unroll
      for (int r = 0; r < 4; ++r) {
        int gm = m0 + wr * 64 + m * 16 + lq * 4 + r;
        int gn = n0 + wc * 64 + n * 16 + l15;
        int b = gm >> 11, s = gm & (CS - 1);
        if (n0 < 2048) {  // Q (pre-scaled)
          float v = (acc[m][n][r] + bq[gn]) * (0.125f * 1.44269504088896340736f);
          int h = gn >> 6, hd = gn & 63;
          Qb[(((size_t)(b * CH + h)) * CS + s) * CHD + hd] = f2bf(v);
        } else if (n0 < 2560) {  // K
          int gn2 = gn - 2048;
          float v = acc[m][n][r] + bk[gn2];
          int gh = gn2 >> 6, hd = gn2 & 63;
          Kb[(((size_t)(b * CG + gh)) * CS + s) * CHD + hd] = f2bf(v);
        } else {  // V -> VT[B,G,HD,S]
          int gn2 = gn - 2560;
          float v = acc[m][n][r] + bv[gn2];
          int gh = gn2 >> 6, hd = gn2 & 63;
          VTb[(((size_t)(b * CG + gh)) * CHD + hd) * CS + s] = f2bf(v);
        }
      }
}

// ------------- output projection GEMM (BK=64, A-only LDS, B->reg) --------
__global__ __launch_bounds__(256, 3) void gemm_out_kernel(
    const uint16_t* __restrict__ A, const uint16_t* __restrict__ Btp,
    const float* __restrict__ bias, float* __restrict__ Cout,
    int M, int N, int Kdim) {
  constexpr int BM = 128, BK = 64, K = 2048, NT = K / BK;  // 32
  constexpr int ASZ = BM * BK;
  __shared__ uint16_t Asm[3 * ASZ];  // 48 KB
  const int tid = threadIdx.x;
  const int w = tid >> 6, l = tid & 63;
  const int wr = w >> 1, wc = w & 1;
  const int l15 = l & 15, lq = l >> 4;

  const int gx = gridDim.x;  // 16
  int bid = blockIdx.y * gx + blockIdx.x;
  const int nwg = gx * gridDim.y;
  bid = (bid & 7) * (nwg >> 3) + (bid >> 3);
  const int m0 = (bid / gx) * BM, n0 = (bid % gx) * 128;
  const int nbb = (n0 >> 4) + wc * 4;

  auto stageA = [&](int buf, int t) {
    uint16_t* base = Asm + buf * ASZ;
    const int k0 = t * BK;
#pragma unroll
    for (int i = 0; i < 4; ++i) {
      int g = i * 256 + tid;
      int row = g >> 3, slot = g & 7;
      int kq = slot ^ (row & 7);
      gload_lds16(A + (size_t)(m0 + row) * K + k0 + kq * 8, base + g * 8);
    }
  };
  auto loadB = [&](bf16x8 (*dst)[4], int t) {
#pragma unroll
    for (int kk = 0; kk < 2; ++kk)
#pragma unroll
      for (int n = 0; n < 4; ++n)
        dst[kk][n] = *(const bf16x8*)(
            Btp + ((((size_t)(nbb + n)) * 64 + (size_t)(2 * t + kk)) << 9) +
            (size_t)l * 8);
  };

  int aOff[2][4];
#pragma unroll
  for (int kk = 0; kk < 2; ++kk)
#pragma unroll
    for (int m = 0; m < 4; ++m) {
      int row = wr * 64 + m * 16 + l15;
      aOff[kk][m] = (row * BK + ((kk * 4 + lq) ^ (row & 7)) * 8) * 2;
    }

  f32x4 acc[4][4] = {};
  bf16x8 brg[2][4];

  loadB(brg, 0);
  stageA(0, 0);
  stageA(1, 1);

  int bt = 0, bs = 2;
  for (int t = 0; t < NT; ++t) {
    if (t < NT - 1) asm volatile("s_waitcnt vmcnt(4)" ::: "memory");
    else            asm volatile("s_waitcnt vmcnt(0)" ::: "memory");
    __builtin_amdgcn_s_barrier();
    asm volatile("" ::: "memory");

    const char* buf = (const char*)(Asm + bt * ASZ);
    bf16x8 af[2][4];
#pragma unroll
    for (int kk = 0; kk < 2; ++kk)
#pragma unroll
      for (int m = 0; m < 4; ++m)
        af[kk][m] = *(const bf16x8*)(buf + aOff[kk][m]);

    __builtin_amdgcn_s_setprio(1);
#pragma unroll
    for (int kk = 0; kk < 2; ++kk)
#pragma unroll
      for (int m = 0; m < 4; ++m)
#pragma unroll
        for (int n = 0; n < 4; ++n)
          acc[m][n] = __builtin_amdgcn_mfma_f32_16x16x32_bf16(
              af[kk][m], brg[kk][n], acc[m][n], 0, 0, 0);
    __builtin_amdgcn_s_setprio(0);

    if (t + 1 < NT) loadB(brg, t + 1);
    if (t + 2 < NT) stageA(bs, t + 2);

    bt = bt == 2 ? 0 : bt + 1;
    bs = bs == 2 ? 0 : bs + 1;
  }

#pragma unroll
  for (int m = 0; m < 4; ++m)
#pragma unroll
    for (int n = 0; n < 4; ++n)
#pragma unroll
      for (int r = 0; r < 4; ++r) {
        int gm = m0 + wr * 64 + m * 16 + lq * 4 + r;
        int gn = n0 + wc * 64 + n * 16 + l15;
        Cout[(size_t)gm * N + gn] = acc[m][n][r] + bias[gn];
      }
}

// ---------------- causal flash attention, balanced pairs, KVBLK=128 ------
// (unchanged from passing R11-R13 version)
__global__ __launch_bounds__(256, 2) void flash_attn_kernel(
    const uint16_t* __restrict__ Q, const uint16_t* __restrict__ K,
    const uint16_t* __restrict__ VT, uint16_t* __restrict__ Aout) {
  constexpr int NQB = CS / 128;  // 16
  constexpr int KV = 128;        // keys per tile
  __shared__ __align__(16) uint16_t Ksm[2][KV * CHD];  // [key][hd] 16KB each
  __shared__ __align__(16) uint16_t Vsm[2][CHD * KV];  // [hd][key] 16KB each
  const int tid = threadIdx.x, w = tid >> 6, l = tid & 63;
  const int l31 = l & 31, hi = l >> 5;
  const int x = blockIdx.x;  // 0..NQB/2-1
  const int h = blockIdx.y, b = blockIdx.z, g = h >> 2;

  const uint16_t* Qbase = Q + ((size_t)(b * CH + h)) * CS * CHD;
  const uint16_t* Kbase = K + ((size_t)(b * CG + g)) * CS * CHD;
  const uint16_t* Vbase = VT + ((size_t)(b * CG + g)) * CHD * CS;

  auto stage = [&](int buf, int kt) {
#pragma unroll
    for (int i = 0; i < 4; ++i) {
      int gK = i * 256 + tid;           // 1024 granules, row=key, 8/row
      int rowK = gK >> 3, slotK = gK & 7;
      int kqK = slotK ^ (rowK & 7);
      gload_lds16(Kbase + ((size_t)kt * KV + rowK) * CHD + kqK * 8,
                  &Ksm[buf][gK * 8]);
    }
#pragma unroll
    for (int i = 0; i < 4; ++i) {
      int gV = i * 256 + tid;           // 1024 granules, row=hd, 16/row
      int rowV = gV >> 4, slotV = gV & 15;
      int kqV = slotV ^ (rowV & 15);
      gload_lds16(Vbase + (size_t)rowV * CS + kt * KV + kqV * 8,
                  &Vsm[buf][gV * 8]);
    }
  };

  int kOff[4][4];
#pragma unroll
  for (int c = 0; c < 4; ++c)
#pragma unroll
    for (int kc = 0; kc < 4; ++kc) {
      int row = c * 32 + l31;
      kOff[c][kc] = ((row * CHD + kc * 16 + hi * 8) * 2) ^ ((row & 7) << 4);
    }
  int vOff[2][8];
#pragma unroll
  for (int c = 0; c < 2; ++c)
#pragma unroll
    for (int ks = 0; ks < 8; ++ks) {
      int row = c * 32 + l31;
      vOff[c][ks] = ((row * KV + ks * 16 + hi * 8) * 2) ^ ((row & 15) << 4);
    }

#pragma unroll 1
  for (int job = 0; job < 2; ++job) {
    const int qb = job == 0 ? (NQB - 1 - x) : x;
    const int qrow = qb * 128 + w * 32 + l31;
    const int wbase = qb * 128 + w * 32;  // wave's FIRST q-row

    bf16x8 qf[4];
#pragma unroll
    for (int kc = 0; kc < 4; ++kc)
      qf[kc] = *(const bf16x8*)(Qbase + (size_t)qrow * CHD + kc * 16 + hi * 8);

    f32x16 o0 = {}, o1 = {};
    float mrun = -3e38f, lrun = 0.f;
    const int nt = qb + 1;

    stage(0, 0);
    asm volatile("s_waitcnt vmcnt(0)" ::: "memory");
    __syncthreads();

    for (int kt = 0; kt < nt; ++kt) {
      const int cur = kt & 1;
      if (kt + 1 < nt) stage(cur ^ 1, kt + 1);

      const char* ksmb = (const char*)Ksm[cur];
      const char* vsmb = (const char*)Vsm[cur];

      f32x16 p0 = {}, p1 = {}, p2 = {}, p3 = {};
      __builtin_amdgcn_s_setprio(1);
#pragma unroll
      for (int kc = 0; kc < 4; ++kc) {
        bf16x8 ka0 = *(const bf16x8*)(ksmb + kOff[0][kc]);
        bf16x8 ka1 = *(const bf16x8*)(ksmb + kOff[1][kc]);
        bf16x8 ka2 = *(const bf16x8*)(ksmb + kOff[2][kc]);
        bf16x8 ka3 = *(const bf16x8*)(ksmb + kOff[3][kc]);
        p0 = __builtin_amdgcn_mfma_f32_32x32x16_bf16(ka0, qf[kc], p0, 0, 0, 0);
        p1 = __builtin_amdgcn_mfma_f32_32x32x16_bf16(ka1, qf[kc], p1, 0, 0, 0);
        p2 = __builtin_amdgcn_mfma_f32_32x32x16_bf16(ka2, qf[kc], p2, 0, 0, 0);
        p3 = __builtin_amdgcn_mfma_f32_32x32x16_bf16(ka3, qf[kc], p3, 0, 0, 0);
      }
      __builtin_amdgcn_s_setprio(0);

      const bool need_mask = (kt * KV + KV - 1 > wbase);
      if (need_mask) {
#pragma unroll
        for (int r = 0; r < 16; ++r) {
          int keyb = kt * KV + (r & 3) + 8 * (r >> 2) + 4 * hi;
          if (keyb > qrow) p0[r] = -3e38f;
          if (keyb + 32 > qrow) p1[r] = -3e38f;
          if (keyb + 64 > qrow) p2[r] = -3e38f;
          if (keyb + 96 > qrow) p3[r] = -3e38f;
        }
      }
      float pmax = -3e38f;
#pragma unroll
      for (int r = 0; r < 16; ++r) {
        pmax = fmaxf(pmax, fmaxf(fmaxf(p0[r], p1[r]), fmaxf(p2[r], p3[r])));
      }
      pmax = fmaxf(pmax, __shfl_xor(pmax, 32));

      if (!__all(pmax <= mrun + 8.f)) {
        float mnew = fmaxf(mrun, pmax);
        float alpha = __builtin_amdgcn_exp2f(mrun - mnew);
#pragma unroll
        for (int r = 0; r < 16; ++r) { o0[r] *= alpha; o1[r] *= alpha; }
        lrun *= alpha;
        mrun = mnew;
      }
      float s = 0.f;
#pragma unroll
      for (int r = 0; r < 16; ++r) {
        float e0 = __builtin_amdgcn_exp2f(p0[r] - mrun);
        float e1 = __builtin_amdgcn_exp2f(p1[r] - mrun);
        float e2 = __builtin_amdgcn_exp2f(p2[r] - mrun);
        float e3 = __builtin_amdgcn_exp2f(p3[r] - mrun);
        p0[r] = e0; p1[r] = e1; p2[r] = e2; p3[r] = e3;
        s += (e0 + e1) + (e2 + e3);
      }
      s += __shfl_xor(s, 32);
      lrun += s;

      u32x4 paw[8];
#pragma unroll
      for (int k = 0; k < 8; ++k) {
        const int base = (k & 1) * 8;
        const int c = k >> 1;
        const f32x16& pc = (c == 0) ? p0 : (c == 1) ? p1 : (c == 2) ? p2 : p3;
        uint32_t c01 = cvtpk_bf16(pc[base + 0], pc[base + 1]);
        uint32_t c23 = cvtpk_bf16(pc[base + 2], pc[base + 3]);
        uint32_t c45 = cvtpk_bf16(pc[base + 4], pc[base + 5]);
        uint32_t c67 = cvtpk_bf16(pc[base + 6], pc[base + 7]);
        pl32swap(c01, c45);
        pl32swap(c23, c67);
        paw[k] = (u32x4){c01, c23, c45, c67};
      }

      __builtin_amdgcn_s_setprio(1);
#pragma unroll
      for (int ks = 0; ks < 8; ++ks) {
        bf16x8 vb0 = *(const bf16x8*)(vsmb + vOff[0][ks]);
        bf16x8 vb1 = *(const bf16x8*)(vsmb + vOff[1][ks]);
        bf16x8 pb = __builtin_bit_cast(bf16x8, paw[ks]);
        o0 = __builtin_amdgcn_mfma_f32_32x32x16_bf16(vb0, pb, o0, 0, 0, 0);
        o1 = __builtin_amdgcn_mfma_f32_32x32x16_bf16(vb1, pb, o1, 0, 0, 0);
      }
      __builtin_amdgcn_s_setprio(0);

      asm volatile("s_waitcnt vmcnt(0)" ::: "memory");
      __syncthreads();
    }

    float invl = 1.f / lrun;
    uint16_t* orow = Aout + ((size_t)b * CS + qrow) * CD + (size_t)h * CHD;
#pragma unroll
    for (int k = 0; k < 8; ++k) {
      int reg = 2 * k;
      int hd = (reg & 3) + 8 * (reg >> 2) + 4 * hi;
      *(uint32_t*)(orow + hd) = cvtpk_bf16(o0[reg] * invl, o0[reg + 1] * invl);
      *(uint32_t*)(orow + hd + 32) = cvtpk_bf16(o1[reg] * invl, o1[reg + 1] * invl);
    }
  }
}

extern "C" void kernel_launch(void* const* d_in, const int* in_sizes, int n_in,
                              void* d_out, int out_size, void* d_ws, size_t ws_size,
                              hipStream_t stream) {
  const float* x = (const float*)d_in[0];
  const float* kv = (const float*)d_in[1];
  const float* Wq = (const float*)d_in[2];
  const float* bq = (const float*)d_in[3];
  const float* Wk = (const float*)d_in[4];
  const float* bk = (const float*)d_in[5];
  const float* Wv = (const float*)d_in[6];
  const float* bv = (const float*)d_in[7];
  const float* Wo = (const float*)d_in[8];
  const float* bo = (const float*)d_in[9];
  float* out = (float*)d_out;

  char* ws = (char*)d_ws;
  uint16_t* xb = (uint16_t*)ws;   ws += (size_t)CB * CS * CD * 2;
  uint16_t* kvb = (uint16_t*)ws;  ws += (size_t)CB * CS * CD * 2;
  uint16_t* WqT = (uint16_t*)ws;  ws += (size_t)CD * CD * 2;        // packed rows 0..2047
  uint16_t* WkT = (uint16_t*)ws;  ws += (size_t)(CG * CHD) * CD * 2;  // 2048..2559
  uint16_t* WvT = (uint16_t*)ws;  ws += (size_t)(CG * CHD) * CD * 2;  // 2560..3071
  uint16_t* WoT = (uint16_t*)ws;  ws += (size_t)CD * CD * 2;        // 3072..5119
  uint16_t* Qb = (uint16_t*)ws;   ws += (size_t)CB * CH * CS * CHD * 2;
  uint16_t* Kb = (uint16_t*)ws;   ws += (size_t)CB * CG * CS * CHD * 2;
  uint16_t* VTb = (uint16_t*)ws;  ws += (size_t)CB * CG * CHD * CS * 2;
  uint16_t* attnb = (uint16_t*)ws;
  (void)WkT; (void)WvT;

  const int NTOK = CB * CS;  // 4096
  const int nel = CB * CS * CD;

  cast_both_kernel<<<2 * nel / 4 / 256, 256, 0, stream>>>(x, kv, xb, kvb, nel);
  transpose_all_kernel<<<dim3(5120 / 32, CD / 32), 256, 0, stream>>>(
      Wq, Wk, Wv, Wo, WqT);

  gemm_qkv_kernel<<<dim3(3072 / 128, NTOK / 128), 256, 0, stream>>>(
      xb, kvb, WqT, bq, bk, bv, Qb, Kb, VTb);

  flash_attn_kernel<<<dim3(CS / 256, CH, CB), 256, 0, stream>>>(Qb, Kb, VTb, attnb);

  gemm_out_kernel<<<dim3(CD / 128, NTOK / 128), 256, 0, stream>>>(
      attnb, WoT, bo, out, NTOK, CD, CD);
}